// Round 7
// baseline (4897.434 us; speedup 1.0000x reference)
//
#include <hip/hip_runtime.h>
#include <hip/hip_cooperative_groups.h>
#include <math.h>

namespace cg = cooperative_groups;

#define TT 12
#define FF 32
#define HH 64
#define OO 8
#define GG 256   // 4*HH
#define NF 4     // NUM_FUTURE
#define BR 16    // rows per gates tile
#define LDW 260  // padded LDS row stride (words); rows rg+4r' -> banks {0,4,8,12}

__device__ __forceinline__ float sigmoidf_(float x){ return 1.f/(1.f+expf(-x)); }

// ================= CSR build =================
__global__ void hist_kernel(const int* __restrict__ dst, int* __restrict__ cnt, int E){
  int e = blockIdx.x*blockDim.x + threadIdx.x;
  if (e < E) atomicAdd(&cnt[dst[e]], 1);
}

__global__ __launch_bounds__(1024) void scan_kernel(const int* __restrict__ cnt,
                                                    int* __restrict__ ptr,
                                                    float* __restrict__ invd, int N){
  __shared__ int buf[1024];
  __shared__ int carry;
  if (threadIdx.x == 0) carry = 0;
  __syncthreads();
  for (int base = 0; base < N; base += 1024){
    int i = base + threadIdx.x;
    int v = (i < N) ? cnt[i] : 0;
    buf[threadIdx.x] = v;
    __syncthreads();
    for (int off = 1; off < 1024; off <<= 1){
      int t = (threadIdx.x >= off) ? buf[threadIdx.x - off] : 0;
      __syncthreads();
      buf[threadIdx.x] += t;
      __syncthreads();
    }
    int incl = buf[threadIdx.x];
    if (i < N){
      ptr[i] = carry + incl - v;
      invd[i] = 1.f / fmaxf((float)v, 1.f);
    }
    __syncthreads();
    if (threadIdx.x == 1023){
      carry += incl;
      if (base + 1024 >= N) ptr[N] = carry;
    }
    __syncthreads();
  }
}

__global__ void fill_kernel(const int* __restrict__ src, const int* __restrict__ dst,
                            const float* __restrict__ ew, const int* __restrict__ ptr,
                            int* __restrict__ fill, int2* __restrict__ csr_sw, int E){
  int e = blockIdx.x*blockDim.x + threadIdx.x;
  if (e >= E) return;
  int d = dst[e];
  int pos = ptr[d] + atomicAdd(&fill[d], 1);
  int2 m; m.x = src[e]; m.y = __float_as_int(ew[e]);
  csr_sw[pos] = m;
}

// ========== SAGE aggregation: t-inner (6 planes/lane), edge-unroll 2 ==========
__global__ __launch_bounds__(256) void sage_gather(
    const float* __restrict__ x, const int* __restrict__ ptr,
    const int2* __restrict__ csr_sw,
    const float* __restrict__ invd, float* __restrict__ aggx, int N){
  int wave = threadIdx.x >> 6, lane = threadIdx.x & 63;
  int f = lane & 31, tp = lane >> 5;
  int n = blockIdx.x*4 + wave;
  if (n >= N) return;
  int beg = ptr[n], end = ptr[n+1];
  float id = invd[n];
  float acc[TT/2];
  #pragma unroll
  for (int th = 0; th < TT/2; ++th) acc[th] = 0.f;
  const size_t plane = (size_t)N*FF;
  int e = beg;
  for (; e+2 <= end; e += 2){
    int2 m0 = csr_sw[e], m1 = csr_sw[e+1];
    const float* p0 = x + (size_t)m0.x*FF + f + (size_t)tp*plane;
    const float* p1 = x + (size_t)m1.x*FF + f + (size_t)tp*plane;
    float w0 = __int_as_float(m0.y), w1 = __int_as_float(m1.y);
    #pragma unroll
    for (int th = 0; th < TT/2; ++th)
      acc[th] += p0[2*th*plane]*w0 + p1[2*th*plane]*w1;
  }
  for (; e < end; ++e){
    int2 m = csr_sw[e];
    const float* p = x + (size_t)m.x*FF + f + (size_t)tp*plane;
    float wv = __int_as_float(m.y);
    #pragma unroll
    for (int th = 0; th < TT/2; ++th)
      acc[th] += p[2*th*plane]*wv;
  }
  #pragma unroll
  for (int th = 0; th < TT/2; ++th)
    aggx[(size_t)(2*th+tp)*plane + (size_t)n*FF + f] = acc[th] * id;  // pre-normalized
}

// ================= SAGE linear: emb = agg@Wr + x@Wroot + b ; xr = relu =====
__global__ __launch_bounds__(256) void sage_gemm(
    const float* __restrict__ x, const float* __restrict__ agg,
    const float* __restrict__ Wr, const float* __restrict__ Wroot,
    const float* __restrict__ b,
    float* __restrict__ emb, float* __restrict__ xr, int N){
  __shared__ float sWr[FF*HH], sWroot[FF*HH];
  for (int i = threadIdx.x; i < FF*HH; i += 256){ sWr[i] = Wr[i]; sWroot[i] = Wroot[i]; }
  __syncthreads();
  int idx = blockIdx.x*256 + threadIdx.x;
  int row = idx >> 6, hh = idx & (HH-1);
  if (row >= TT*N) return;
  const float* xv = x   + (size_t)row*FF;
  const float* av = agg + (size_t)row*FF;
  float acc = b[hh];
  #pragma unroll
  for (int k = 0; k < FF; ++k)
    acc += av[k]*sWr[k*HH+hh] + xv[k]*sWroot[k*HH+hh];
  emb[(size_t)row*HH + hh] = acc;
  xr[(size_t)row*HH + hh]  = fmaxf(acc, 0.f);
}

// ========== xr aggregation: t-inner (12 acc), edge-unroll 2 ==========
__global__ __launch_bounds__(256) void xr_gather(
    const float* __restrict__ xr, const int* __restrict__ ptr,
    const int2* __restrict__ csr_sw,
    const float* __restrict__ invd, float* __restrict__ xr_agg, int N){
  int wave = threadIdx.x >> 6, lane = threadIdx.x & 63;
  int n = blockIdx.x*4 + wave;
  if (n >= N) return;
  int beg = ptr[n], end = ptr[n+1];
  float id = invd[n];
  float acc[TT];
  #pragma unroll
  for (int t = 0; t < TT; ++t) acc[t] = 0.f;
  const size_t plane = (size_t)N*HH;
  int e = beg;
  for (; e+2 <= end; e += 2){
    int2 m0 = csr_sw[e], m1 = csr_sw[e+1];
    const float* p0 = xr + (size_t)m0.x*HH + lane;
    const float* p1 = xr + (size_t)m1.x*HH + lane;
    float w0 = __int_as_float(m0.y), w1 = __int_as_float(m1.y);
    #pragma unroll
    for (int t = 0; t < TT; ++t)
      acc[t] += p0[t*plane]*w0 + p1[t*plane]*w1;
  }
  for (; e < end; ++e){
    int2 m = csr_sw[e];
    const float* p = xr + (size_t)m.x*HH + lane;
    float wv = __int_as_float(m.y);
    #pragma unroll
    for (int t = 0; t < TT; ++t)
      acc[t] += p[t*plane]*wv;
  }
  #pragma unroll
  for (int t = 0; t < TT; ++t)
    xr_agg[(size_t)t*plane + (size_t)n*HH + lane] = acc[t] * id;  // pre-normalized
}

// ====== persistent cooperative kernel: entire 24-step recurrence ======
// grid-stride over node tiles; one grid.sync per step.
__global__ __launch_bounds__(256, 4) void lstm_persist(
    const float* __restrict__ xr, const float* __restrict__ xr_agg,
    float* __restrict__ hA, float* __restrict__ hB, float* __restrict__ c,
    const float* __restrict__ invd, const int* __restrict__ ptr,
    const int2* __restrict__ csr_sw,
    const float* __restrict__ W1r, const float* __restrict__ W1root, const float* __restrict__ b1,
    const float* __restrict__ W2r, const float* __restrict__ W2root, const float* __restrict__ b2,
    float* __restrict__ h2s, int N, int ntiles){
  cg::grid_group grid = cg::this_grid();
  __shared__ float lds[BR][LDW];
  int tid = threadIdx.x, wave = tid >> 6, lane = tid & 63;

  float* hp = hA; float* hn = hB;
  for (int s = 0; s < 2*TT; ++s){
    const float* Wr    = (s < TT) ? W1r    : W2r;
    const float* Wroot = (s < TT) ? W1root : W2root;
    const float* bias  = (s < TT) ? b1     : b2;
    int t = (s < TT) ? s : s - TT;
    const float* xr_t    = xr     + (size_t)t*N*HH;
    const float* xragg_t = xr_agg + (size_t)t*N*HH;

    for (int tile = blockIdx.x; tile < ntiles; tile += gridDim.x){
      int base = tile * BR;

      // ---- Phase A: gather h_agg (unroll-8) + stage inputs ----
      for (int r4 = 0; r4 < 4; ++r4){
        int r = wave*4 + r4;
        int n = base + r;
        if (n < N){
          float id = invd[n];
          int beg = ptr[n], end = ptr[n+1];
          float a0=0.f,a1=0.f,a2=0.f,a3=0.f,a4=0.f,a5=0.f,a6=0.f,a7=0.f;
          int e = beg;
          for (; e+8 <= end; e += 8){
            int2 m0=csr_sw[e+0], m1=csr_sw[e+1], m2=csr_sw[e+2], m3=csr_sw[e+3];
            int2 m4=csr_sw[e+4], m5=csr_sw[e+5], m6=csr_sw[e+6], m7=csr_sw[e+7];
            a0 += hp[(size_t)m0.x*HH+lane]*__int_as_float(m0.y);
            a1 += hp[(size_t)m1.x*HH+lane]*__int_as_float(m1.y);
            a2 += hp[(size_t)m2.x*HH+lane]*__int_as_float(m2.y);
            a3 += hp[(size_t)m3.x*HH+lane]*__int_as_float(m3.y);
            a4 += hp[(size_t)m4.x*HH+lane]*__int_as_float(m4.y);
            a5 += hp[(size_t)m5.x*HH+lane]*__int_as_float(m5.y);
            a6 += hp[(size_t)m6.x*HH+lane]*__int_as_float(m6.y);
            a7 += hp[(size_t)m7.x*HH+lane]*__int_as_float(m7.y);
          }
          for (; e < end; ++e){
            int2 m = csr_sw[e];
            a0 += hp[(size_t)m.x*HH+lane]*__int_as_float(m.y);
          }
          lds[r][ 64+lane] = (((a0+a1)+(a2+a3))+((a4+a5)+(a6+a7))) * id;
          lds[r][    lane] = xragg_t[(size_t)n*HH + lane];
          lds[r][128+lane] = xr_t   [(size_t)n*HH + lane];
          lds[r][192+lane] = hp     [(size_t)n*HH + lane];
        } else {
          lds[r][lane] = lds[r][64+lane] = lds[r][128+lane] = lds[r][192+lane] = 0.f;
        }
      }
      __syncthreads();

      // ---- Phase B: GEMM; wave owns cols [64w,64w+64); 4 rows x 4 cols/thread ----
      int cg2 = lane & 15, rg = lane >> 4;
      int j0 = wave*64 + cg2*4;
      float acc[4][4];
      {
        float4 bv = *(const float4*)&bias[j0];
        #pragma unroll
        for (int r = 0; r < 4; ++r){
          acc[r][0]=bv.x; acc[r][1]=bv.y; acc[r][2]=bv.z; acc[r][3]=bv.w;
        }
      }
      #pragma unroll 4
      for (int k = 0; k < 128; k += 4){
        float4 w0 = *(const float4*)&Wr[(size_t)(k+0)*GG + j0];
        float4 w1 = *(const float4*)&Wr[(size_t)(k+1)*GG + j0];
        float4 w2 = *(const float4*)&Wr[(size_t)(k+2)*GG + j0];
        float4 w3 = *(const float4*)&Wr[(size_t)(k+3)*GG + j0];
        #pragma unroll
        for (int rp = 0; rp < 4; ++rp){
          float4 a = *(const float4*)&lds[rg + 4*rp][k];
          acc[rp][0] += a.x*w0.x + a.y*w1.x + a.z*w2.x + a.w*w3.x;
          acc[rp][1] += a.x*w0.y + a.y*w1.y + a.z*w2.y + a.w*w3.y;
          acc[rp][2] += a.x*w0.z + a.y*w1.z + a.z*w2.z + a.w*w3.z;
          acc[rp][3] += a.x*w0.w + a.y*w1.w + a.z*w2.w + a.w*w3.w;
        }
      }
      #pragma unroll 4
      for (int k = 0; k < 128; k += 4){
        float4 w0 = *(const float4*)&Wroot[(size_t)(k+0)*GG + j0];
        float4 w1 = *(const float4*)&Wroot[(size_t)(k+1)*GG + j0];
        float4 w2 = *(const float4*)&Wroot[(size_t)(k+2)*GG + j0];
        float4 w3 = *(const float4*)&Wroot[(size_t)(k+3)*GG + j0];
        #pragma unroll
        for (int rp = 0; rp < 4; ++rp){
          float4 a = *(const float4*)&lds[rg + 4*rp][128+k];
          acc[rp][0] += a.x*w0.x + a.y*w1.x + a.z*w2.x + a.w*w3.x;
          acc[rp][1] += a.x*w0.y + a.y*w1.y + a.z*w2.y + a.w*w3.y;
          acc[rp][2] += a.x*w0.z + a.y*w1.z + a.z*w2.z + a.w*w3.z;
          acc[rp][3] += a.x*w0.w + a.y*w1.w + a.z*w2.w + a.w*w3.w;
        }
      }
      __syncthreads();
      #pragma unroll
      for (int rp = 0; rp < 4; ++rp){
        float4 g4; g4.x=acc[rp][0]; g4.y=acc[rp][1]; g4.z=acc[rp][2]; g4.w=acc[rp][3];
        *(float4*)&lds[rg + 4*rp][j0] = g4;    // gates
      }
      __syncthreads();

      // ---- Phase C: cell update ----
      for (int r = wave; r < BR; r += 4){
        int n = base + r;
        if (n >= N) continue;
        float gi = lds[r][lane], gf = lds[r][64+lane], gg2 = lds[r][128+lane], go = lds[r][192+lane];
        float cn = sigmoidf_(gf)*c[(size_t)n*HH+lane] + sigmoidf_(gi)*tanhf(gg2);
        float hn2 = sigmoidf_(go)*tanhf(cn);
        c[(size_t)n*HH+lane] = cn;
        hn[(size_t)n*HH+lane] = hn2;
        if (s >= TT + (TT-NF)) h2s[(size_t)(s - TT - (TT-NF))*N*HH + (size_t)n*HH + lane] = hn2;
      }
      __syncthreads();   // lds reused by next tile's Phase A
    }
    grid.sync();
    float* tmp = hp; hp = hn; hn = tmp;
  }
}

// ============ fallback: per-step h aggregation (one wave per node) ============
__global__ __launch_bounds__(256) void hgather_step(
    const float* __restrict__ h_prev, const int* __restrict__ ptr,
    const int2* __restrict__ csr_sw, const float* __restrict__ invd,
    float* __restrict__ h_agg, int N){
  int wave = threadIdx.x >> 6, lane = threadIdx.x & 63;
  int n = blockIdx.x*4 + wave;
  if (n >= N) return;
  int beg = ptr[n], end = ptr[n+1];
  float a0=0.f,a1=0.f,a2=0.f,a3=0.f,a4=0.f,a5=0.f,a6=0.f,a7=0.f;
  int e = beg;
  for (; e+8 <= end; e += 8){
    int2 m0=csr_sw[e+0], m1=csr_sw[e+1], m2=csr_sw[e+2], m3=csr_sw[e+3];
    int2 m4=csr_sw[e+4], m5=csr_sw[e+5], m6=csr_sw[e+6], m7=csr_sw[e+7];
    a0 += h_prev[(size_t)m0.x*HH+lane]*__int_as_float(m0.y);
    a1 += h_prev[(size_t)m1.x*HH+lane]*__int_as_float(m1.y);
    a2 += h_prev[(size_t)m2.x*HH+lane]*__int_as_float(m2.y);
    a3 += h_prev[(size_t)m3.x*HH+lane]*__int_as_float(m3.y);
    a4 += h_prev[(size_t)m4.x*HH+lane]*__int_as_float(m4.y);
    a5 += h_prev[(size_t)m5.x*HH+lane]*__int_as_float(m5.y);
    a6 += h_prev[(size_t)m6.x*HH+lane]*__int_as_float(m6.y);
    a7 += h_prev[(size_t)m7.x*HH+lane]*__int_as_float(m7.y);
  }
  for (; e < end; ++e){
    int2 m = csr_sw[e];
    a0 += h_prev[(size_t)m.x*HH+lane]*__int_as_float(m.y);
  }
  h_agg[(size_t)n*HH+lane] = (((a0+a1)+(a2+a3))+((a4+a5)+(a6+a7))) * invd[n];
}

// ============ fallback: gates GEMM + LSTM cell, BR nodes/block ======
__global__ __launch_bounds__(256) void gates_cell_step(
    const float* __restrict__ xr_t, const float* __restrict__ xragg_t,
    const float* __restrict__ h_agg,
    const float* __restrict__ h_prev, float* __restrict__ h_next,
    float* __restrict__ c,
    const float* __restrict__ Wr, const float* __restrict__ Wroot,
    const float* __restrict__ b,
    float* __restrict__ h2_store, int N){
  __shared__ float lds[BR][LDW];
  int tid = threadIdx.x, wave = tid >> 6, lane = tid & 63;
  int base = blockIdx.x * BR;

  for (int r = 0; r < BR; ++r){
    int n = base + r;
    int k = tid;
    float v;
    if (n < N){
      if      (k < 64)  v = xragg_t[(size_t)n*HH + k];
      else if (k < 128) v = h_agg  [(size_t)n*HH + (k-64)];
      else if (k < 192) v = xr_t   [(size_t)n*HH + (k-128)];
      else              v = h_prev [(size_t)n*HH + (k-192)];
    } else v = 0.f;
    lds[r][k] = v;
  }
  __syncthreads();

  int cg2 = lane & 15, rg = lane >> 4;
  int j0 = wave*64 + cg2*4;
  float acc[4][4];
  {
    float4 bv = *(const float4*)&b[j0];
    #pragma unroll
    for (int r = 0; r < 4; ++r){
      acc[r][0]=bv.x; acc[r][1]=bv.y; acc[r][2]=bv.z; acc[r][3]=bv.w;
    }
  }
  #pragma unroll 4
  for (int k = 0; k < 128; k += 4){
    float4 w0 = *(const float4*)&Wr[(size_t)(k+0)*GG + j0];
    float4 w1 = *(const float4*)&Wr[(size_t)(k+1)*GG + j0];
    float4 w2 = *(const float4*)&Wr[(size_t)(k+2)*GG + j0];
    float4 w3 = *(const float4*)&Wr[(size_t)(k+3)*GG + j0];
    #pragma unroll
    for (int rp = 0; rp < 4; ++rp){
      float4 a = *(const float4*)&lds[rg + 4*rp][k];
      acc[rp][0] += a.x*w0.x + a.y*w1.x + a.z*w2.x + a.w*w3.x;
      acc[rp][1] += a.x*w0.y + a.y*w1.y + a.z*w2.y + a.w*w3.y;
      acc[rp][2] += a.x*w0.z + a.y*w1.z + a.z*w2.z + a.w*w3.z;
      acc[rp][3] += a.x*w0.w + a.y*w1.w + a.z*w2.w + a.w*w3.w;
    }
  }
  #pragma unroll 4
  for (int k = 0; k < 128; k += 4){
    float4 w0 = *(const float4*)&Wroot[(size_t)(k+0)*GG + j0];
    float4 w1 = *(const float4*)&Wroot[(size_t)(k+1)*GG + j0];
    float4 w2 = *(const float4*)&Wroot[(size_t)(k+2)*GG + j0];
    float4 w3 = *(const float4*)&Wroot[(size_t)(k+3)*GG + j0];
    #pragma unroll
    for (int rp = 0; rp < 4; ++rp){
      float4 a = *(const float4*)&lds[rg + 4*rp][128+k];
      acc[rp][0] += a.x*w0.x + a.y*w1.x + a.z*w2.x + a.w*w3.x;
      acc[rp][1] += a.x*w0.y + a.y*w1.y + a.z*w2.y + a.w*w3.y;
      acc[rp][2] += a.x*w0.z + a.y*w1.z + a.z*w2.z + a.w*w3.z;
      acc[rp][3] += a.x*w0.w + a.y*w1.w + a.z*w2.w + a.w*w3.w;
    }
  }
  __syncthreads();
  #pragma unroll
  for (int rp = 0; rp < 4; ++rp){
    float4 g4; g4.x=acc[rp][0]; g4.y=acc[rp][1]; g4.z=acc[rp][2]; g4.w=acc[rp][3];
    *(float4*)&lds[rg + 4*rp][j0] = g4;
  }
  __syncthreads();

  for (int r = wave; r < BR; r += 4){
    int n = base + r;
    if (n >= N) continue;
    float gi = lds[r][lane], gf = lds[r][64+lane], gg2 = lds[r][128+lane], go = lds[r][192+lane];
    float cn = sigmoidf_(gf)*c[(size_t)n*HH+lane] + sigmoidf_(gi)*tanhf(gg2);
    float hn = sigmoidf_(go)*tanhf(cn);
    c[(size_t)n*HH+lane] = cn;
    h_next[(size_t)n*HH+lane] = hn;
    if (h2_store) h2_store[(size_t)n*HH+lane] = hn;
  }
}

// ================= output head =================
__global__ void out_gemm(const float* __restrict__ xr8, const float* __restrict__ h2s,
                         const float* __restrict__ Wout, const float* __restrict__ bout,
                         float* __restrict__ out, int N){
  int idx = blockIdx.x*blockDim.x + threadIdx.x;
  if (idx >= NF*N*OO) return;
  int o = idx & (OO-1);
  int row = idx >> 3;                     // tt*N + n
  const float* xv = xr8 + (size_t)row*HH;
  const float* hv = h2s + (size_t)row*HH;
  float acc = bout[o];
  #pragma unroll
  for (int k = 0; k < HH; ++k)
    acc += xv[k]*Wout[k*OO+o] + hv[k]*Wout[(HH+k)*OO+o];
  out[idx] = acc;
}

__global__ void copyk(const float* __restrict__ s, float* __restrict__ d, int n){
  int i = blockIdx.x*blockDim.x + threadIdx.x;
  if (i < n) d[i] = s[i];
}

extern "C" void kernel_launch(void* const* d_in, const int* in_sizes, int n_in,
                              void* d_out, int out_size, void* d_ws, size_t ws_size,
                              hipStream_t stream){
  const float* x      = (const float*)d_in[0];
  const int*   ei     = (const int*)  d_in[1];
  const float* ew     = (const float*)d_in[2];
  const float* sWr    = (const float*)d_in[3];
  const float* sWroot = (const float*)d_in[4];
  const float* sb     = (const float*)d_in[5];
  const float* l1Wr   = (const float*)d_in[6];
  const float* l1Wroot= (const float*)d_in[7];
  const float* l1b    = (const float*)d_in[8];
  const float* l2Wr   = (const float*)d_in[9];
  const float* l2Wroot= (const float*)d_in[10];
  const float* l2b    = (const float*)d_in[11];
  const float* Wout   = (const float*)d_in[12];
  const float* bout   = (const float*)d_in[13];

  const int E = in_sizes[2];
  const int N = in_sizes[0] / (TT*FF);
  const int* src = ei;
  const int* dst = ei + E;

  float* out0   = (float*)d_out;              // [4,N,8]
  float* c2out  = out0 + (size_t)NF*N*OO;     // [N,64]
  float* embout = c2out + (size_t)N*HH;       // [12,N,64]

  float* w = (float*)d_ws;
  float* xr     = w;  w += (size_t)TT*N*HH;
  float* xr_agg = w;  w += (size_t)TT*N*HH;
  float* agg_x  = xr_agg;                     // alias: dead before xr_agg written
  float* hA     = w;  w += (size_t)N*HH;
  float* hB     = w;  w += (size_t)N*HH;
  float* cbuf   = w;  w += (size_t)N*HH;
  float* haggb  = w;  w += (size_t)N*HH;      // fallback path only
  float* h2s    = w;  w += (size_t)NF*N*HH;
  float* invd   = w;  w += N;
  int*   cnt    = (int*)w;  w += N;
  int*   fill   = (int*)w;  w += N;
  int*   ptr    = (int*)w;  w += (N+2);       // keep int2 array 8B-aligned
  int2*  csr_sw = (int2*)w; w += (size_t)2*E;

  hipMemsetAsync(cnt,  0, (size_t)N*4, stream);
  hipMemsetAsync(fill, 0, (size_t)N*4, stream);
  hipMemsetAsync(hA,   0, (size_t)N*HH*4, stream);  // h0
  hipMemsetAsync(cbuf, 0, (size_t)N*HH*4, stream);  // c0

  hist_kernel<<<(E+255)/256, 256, 0, stream>>>(dst, cnt, E);
  scan_kernel<<<1, 1024, 0, stream>>>(cnt, ptr, invd, N);
  fill_kernel<<<(E+255)/256, 256, 0, stream>>>(src, dst, ew, ptr, fill, csr_sw, E);

  sage_gather<<<(N+3)/4, 256, 0, stream>>>(x, ptr, csr_sw, invd, agg_x, N);
  sage_gemm<<<((size_t)TT*N*HH+255)/256, 256, 0, stream>>>(x, agg_x, sWr, sWroot, sb,
                                                           embout, xr, N);
  xr_gather<<<(N+3)/4, 256, 0, stream>>>(xr, ptr, csr_sw, invd, xr_agg, N);

  const int ntiles = (N + BR - 1) / BR;   // 1250

  // Query real cooperative capacity (host-only queries; graph-capture-safe).
  int dev = 0; hipGetDevice(&dev);
  int numCU = 0;
  hipDeviceGetAttribute(&numCU, hipDeviceAttributeMultiprocessorCount, dev);
  int maxBlkPerCU = 0;
  hipError_t occErr = hipOccupancyMaxActiveBlocksPerMultiprocessor(
      &maxBlkPerCU, (const void*)lstm_persist, 256, 0);
  long capacity = (long)maxBlkPerCU * (long)numCU;

  if (occErr == hipSuccess && capacity >= 256){
    int grid = (int)((capacity < (long)ntiles) ? capacity : (long)ntiles);
    const float* a_xr = xr;  const float* a_xragg = xr_agg;
    float* a_hA = hA; float* a_hB = hB; float* a_c = cbuf;
    const float* a_invd = invd; const int* a_ptr = ptr; const int2* a_csr = csr_sw;
    const float* a_w1r = l1Wr; const float* a_w1o = l1Wroot; const float* a_b1 = l1b;
    const float* a_w2r = l2Wr; const float* a_w2o = l2Wroot; const float* a_b2 = l2b;
    float* a_h2s = h2s; int a_N = N; int a_ntiles = ntiles;
    void* args[] = { (void*)&a_xr, (void*)&a_xragg, (void*)&a_hA, (void*)&a_hB, (void*)&a_c,
                     (void*)&a_invd, (void*)&a_ptr, (void*)&a_csr,
                     (void*)&a_w1r, (void*)&a_w1o, (void*)&a_b1,
                     (void*)&a_w2r, (void*)&a_w2o, (void*)&a_b2,
                     (void*)&a_h2s, (void*)&a_N, (void*)&a_ntiles };
    hipLaunchCooperativeKernel((const void*)lstm_persist, dim3(grid), dim3(256),
                               args, 0, stream);
  } else {
    // fallback: R5-verified split-kernel recurrence
    const int gBlocks = (N+3)/4;
    float* hp = hA; float* hn = hB;
    for (int t = 0; t < TT; ++t){
      hgather_step<<<gBlocks, 256, 0, stream>>>(hp, ptr, csr_sw, invd, haggb, N);
      gates_cell_step<<<ntiles, 256, 0, stream>>>(xr + (size_t)t*N*HH, xr_agg + (size_t)t*N*HH,
                                                  haggb, hp, hn, cbuf,
                                                  l1Wr, l1Wroot, l1b, nullptr, N);
      float* tmp = hp; hp = hn; hn = tmp;
    }
    for (int t = 0; t < TT; ++t){
      float* store = (t >= TT-NF) ? (h2s + (size_t)(t-(TT-NF))*N*HH) : nullptr;
      hgather_step<<<gBlocks, 256, 0, stream>>>(hp, ptr, csr_sw, invd, haggb, N);
      gates_cell_step<<<ntiles, 256, 0, stream>>>(xr + (size_t)t*N*HH, xr_agg + (size_t)t*N*HH,
                                                  haggb, hp, hn, cbuf,
                                                  l2Wr, l2Wroot, l2b, store, N);
      float* tmp = hp; hp = hn; hn = tmp;
    }
  }

  out_gemm<<<((size_t)NF*N*OO+255)/256, 256, 0, stream>>>(xr + (size_t)(TT-NF)*N*HH, h2s,
                                                          Wout, bout, out0, N);
  copyk<<<((size_t)N*HH+255)/256, 256, 0, stream>>>(cbuf, c2out, N*HH);
}

// Round 8
// 3093.053 us; speedup vs baseline: 1.5834x; 1.5834x over previous
//
#include <hip/hip_runtime.h>
#include <hip/hip_cooperative_groups.h>
#include <math.h>

namespace cg = cooperative_groups;

#define TT 12
#define FF 32
#define HH 64
#define OO 8
#define GG 256   // 4*HH
#define NF 4     // NUM_FUTURE
#define BR 16    // rows per block (fallback gates / gx_gemm)
#define BRP 20   // rows per block (persist layer kernel) -> N/20 = 1000 tiles
#define LDW 260  // padded LDS row stride (words)

__device__ __forceinline__ float sigmoidf_(float x){ return 1.f/(1.f+expf(-x)); }

// ================= CSR build =================
__global__ void hist_kernel(const int* __restrict__ dst, int* __restrict__ cnt, int E){
  int e = blockIdx.x*blockDim.x + threadIdx.x;
  if (e < E) atomicAdd(&cnt[dst[e]], 1);
}

__global__ __launch_bounds__(1024) void scan_kernel(const int* __restrict__ cnt,
                                                    int* __restrict__ ptr,
                                                    float* __restrict__ invd, int N){
  __shared__ int buf[1024];
  __shared__ int carry;
  if (threadIdx.x == 0) carry = 0;
  __syncthreads();
  for (int base = 0; base < N; base += 1024){
    int i = base + threadIdx.x;
    int v = (i < N) ? cnt[i] : 0;
    buf[threadIdx.x] = v;
    __syncthreads();
    for (int off = 1; off < 1024; off <<= 1){
      int t = (threadIdx.x >= off) ? buf[threadIdx.x - off] : 0;
      __syncthreads();
      buf[threadIdx.x] += t;
      __syncthreads();
    }
    int incl = buf[threadIdx.x];
    if (i < N){
      ptr[i] = carry + incl - v;
      invd[i] = 1.f / fmaxf((float)v, 1.f);
    }
    __syncthreads();
    if (threadIdx.x == 1023){
      carry += incl;
      if (base + 1024 >= N) ptr[N] = carry;
    }
    __syncthreads();
  }
}

__global__ void fill_kernel(const int* __restrict__ src, const int* __restrict__ dst,
                            const float* __restrict__ ew, const int* __restrict__ ptr,
                            int* __restrict__ fill, int2* __restrict__ csr_sw, int E){
  int e = blockIdx.x*blockDim.x + threadIdx.x;
  if (e >= E) return;
  int d = dst[e];
  int pos = ptr[d] + atomicAdd(&fill[d], 1);
  int2 m; m.x = src[e]; m.y = __float_as_int(ew[e]);
  csr_sw[pos] = m;
}

// ========== SAGE aggregation: t-inner (6 planes/lane), edge-unroll 2 ==========
__global__ __launch_bounds__(256) void sage_gather(
    const float* __restrict__ x, const int* __restrict__ ptr,
    const int2* __restrict__ csr_sw,
    const float* __restrict__ invd, float* __restrict__ aggx, int N){
  int wave = threadIdx.x >> 6, lane = threadIdx.x & 63;
  int f = lane & 31, tp = lane >> 5;
  int n = blockIdx.x*4 + wave;
  if (n >= N) return;
  int beg = ptr[n], end = ptr[n+1];
  float id = invd[n];
  float acc[TT/2];
  #pragma unroll
  for (int th = 0; th < TT/2; ++th) acc[th] = 0.f;
  const size_t plane = (size_t)N*FF;
  int e = beg;
  for (; e+2 <= end; e += 2){
    int2 m0 = csr_sw[e], m1 = csr_sw[e+1];
    const float* p0 = x + (size_t)m0.x*FF + f + (size_t)tp*plane;
    const float* p1 = x + (size_t)m1.x*FF + f + (size_t)tp*plane;
    float w0 = __int_as_float(m0.y), w1 = __int_as_float(m1.y);
    #pragma unroll
    for (int th = 0; th < TT/2; ++th)
      acc[th] += p0[2*th*plane]*w0 + p1[2*th*plane]*w1;
  }
  for (; e < end; ++e){
    int2 m = csr_sw[e];
    const float* p = x + (size_t)m.x*FF + f + (size_t)tp*plane;
    float wv = __int_as_float(m.y);
    #pragma unroll
    for (int th = 0; th < TT/2; ++th)
      acc[th] += p[2*th*plane]*wv;
  }
  #pragma unroll
  for (int th = 0; th < TT/2; ++th)
    aggx[(size_t)(2*th+tp)*plane + (size_t)n*FF + f] = acc[th] * id;  // pre-normalized
}

// ================= SAGE linear: emb = agg@Wr + x@Wroot + b ; xr = relu =====
__global__ __launch_bounds__(256) void sage_gemm(
    const float* __restrict__ x, const float* __restrict__ agg,
    const float* __restrict__ Wr, const float* __restrict__ Wroot,
    const float* __restrict__ b,
    float* __restrict__ emb, float* __restrict__ xr, int N){
  __shared__ float sWr[FF*HH], sWroot[FF*HH];
  for (int i = threadIdx.x; i < FF*HH; i += 256){ sWr[i] = Wr[i]; sWroot[i] = Wroot[i]; }
  __syncthreads();
  int idx = blockIdx.x*256 + threadIdx.x;
  int row = idx >> 6, hh = idx & (HH-1);
  if (row >= TT*N) return;
  const float* xv = x   + (size_t)row*FF;
  const float* av = agg + (size_t)row*FF;
  float acc = b[hh];
  #pragma unroll
  for (int k = 0; k < FF; ++k)
    acc += av[k]*sWr[k*HH+hh] + xv[k]*sWroot[k*HH+hh];
  emb[(size_t)row*HH + hh] = acc;
  xr[(size_t)row*HH + hh]  = fmaxf(acc, 0.f);
}

// ========== xr aggregation: t-inner (12 acc), edge-unroll 2 ==========
__global__ __launch_bounds__(256) void xr_gather(
    const float* __restrict__ xr, const int* __restrict__ ptr,
    const int2* __restrict__ csr_sw,
    const float* __restrict__ invd, float* __restrict__ xr_agg, int N){
  int wave = threadIdx.x >> 6, lane = threadIdx.x & 63;
  int n = blockIdx.x*4 + wave;
  if (n >= N) return;
  int beg = ptr[n], end = ptr[n+1];
  float id = invd[n];
  float acc[TT];
  #pragma unroll
  for (int t = 0; t < TT; ++t) acc[t] = 0.f;
  const size_t plane = (size_t)N*HH;
  int e = beg;
  for (; e+2 <= end; e += 2){
    int2 m0 = csr_sw[e], m1 = csr_sw[e+1];
    const float* p0 = xr + (size_t)m0.x*HH + lane;
    const float* p1 = xr + (size_t)m1.x*HH + lane;
    float w0 = __int_as_float(m0.y), w1 = __int_as_float(m1.y);
    #pragma unroll
    for (int t = 0; t < TT; ++t)
      acc[t] += p0[t*plane]*w0 + p1[t*plane]*w1;
  }
  for (; e < end; ++e){
    int2 m = csr_sw[e];
    const float* p = xr + (size_t)m.x*HH + lane;
    float wv = __int_as_float(m.y);
    #pragma unroll
    for (int t = 0; t < TT; ++t)
      acc[t] += p[t*plane]*wv;
  }
  #pragma unroll
  for (int t = 0; t < TT; ++t)
    xr_agg[(size_t)t*plane + (size_t)n*HH + lane] = acc[t] * id;  // pre-normalized
}

// ====== weight packing: out[128][256] = rows [row_off,row_off+64) of Wr then Wroot ======
__global__ void pack_w(const float* __restrict__ Wr, const float* __restrict__ Wroot,
                       int row_off, float* __restrict__ out){
  int idx = blockIdx.x*256 + threadIdx.x;
  if (idx >= 128*GG) return;
  int k = idx >> 8, j = idx & (GG-1);
  out[idx] = (k < 64) ? Wr[(size_t)(row_off+k)*GG + j]
                      : Wroot[(size_t)(row_off + k - 64)*GG + j];
}

// ====== gx = bias + [xr_agg | xr] @ Wx   over all 12*N rows ======
__global__ __launch_bounds__(256) void gx_gemm(
    const float* __restrict__ xr_agg, const float* __restrict__ xr,
    const float* __restrict__ Wx, const float* __restrict__ bias,
    float* __restrict__ gx, int Mrows){
  __shared__ float lds[BR][132];
  int tid = threadIdx.x, wave = tid >> 6, lane = tid & 63;
  int base = blockIdx.x * BR;
  for (int idx = tid; idx < BR*128; idx += 256){
    int r = idx >> 7, k = idx & 127;
    int rr = base + r;
    float v = 0.f;
    if (rr < Mrows) v = (k < 64) ? xr_agg[(size_t)rr*HH + k] : xr[(size_t)rr*HH + (k-64)];
    lds[r][k] = v;
  }
  __syncthreads();
  int cg2 = lane & 15, rg = lane >> 4;
  int j0 = wave*64 + cg2*4;
  float acc[4][4];
  {
    float4 bv = *(const float4*)&bias[j0];
    #pragma unroll
    for (int r = 0; r < 4; ++r){ acc[r][0]=bv.x; acc[r][1]=bv.y; acc[r][2]=bv.z; acc[r][3]=bv.w; }
  }
  #pragma unroll 4
  for (int k = 0; k < 128; k += 4){
    float4 w0 = *(const float4*)&Wx[(size_t)(k+0)*GG + j0];
    float4 w1 = *(const float4*)&Wx[(size_t)(k+1)*GG + j0];
    float4 w2 = *(const float4*)&Wx[(size_t)(k+2)*GG + j0];
    float4 w3 = *(const float4*)&Wx[(size_t)(k+3)*GG + j0];
    #pragma unroll
    for (int rp = 0; rp < 4; ++rp){
      float4 a = *(const float4*)&lds[rg + 4*rp][k];
      acc[rp][0] += a.x*w0.x + a.y*w1.x + a.z*w2.x + a.w*w3.x;
      acc[rp][1] += a.x*w0.y + a.y*w1.y + a.z*w2.y + a.w*w3.y;
      acc[rp][2] += a.x*w0.z + a.y*w1.z + a.z*w2.z + a.w*w3.z;
      acc[rp][3] += a.x*w0.w + a.y*w1.w + a.z*w2.w + a.w*w3.w;
    }
  }
  #pragma unroll
  for (int rp = 0; rp < 4; ++rp){
    int rr = base + rg + 4*rp;
    if (rr < Mrows){
      float4 g4; g4.x=acc[rp][0]; g4.y=acc[rp][1]; g4.z=acc[rp][2]; g4.w=acc[rp][3];
      *(float4*)&gx[(size_t)rr*GG + j0] = g4;
    }
  }
}

// ====== persistent cooperative: ONE layer (12 steps), K=128 h-part only ======
// grid must equal ntiles = ceil(N/BRP). gx holds bias + x-part of gates.
__global__ __launch_bounds__(256, 4) void lstm_layer(
    const float* __restrict__ gx, const float* __restrict__ Wh,
    float* __restrict__ hA, float* __restrict__ hB, float* __restrict__ c,
    const float* __restrict__ invd, const int* __restrict__ ptr,
    const int2* __restrict__ csr_sw,
    float* __restrict__ h2s, int N, int store_from){
  cg::grid_group grid = cg::this_grid();
  __shared__ float lds[BRP][LDW];
  int tid = threadIdx.x, wave = tid >> 6, lane = tid & 63;
  int base = blockIdx.x * BRP;

  float* hp = hA; float* hn = hB;
  for (int t = 0; t < TT; ++t){
    const float* gx_t = gx + (size_t)t*N*GG;

    // ---- Phase A: gather h_agg (unroll-8) + stage [h_agg | h], K=128 ----
    for (int r5 = 0; r5 < 5; ++r5){
      int r = wave*5 + r5;
      int n = base + r;
      if (n < N){
        float id = invd[n];
        int beg = ptr[n], end = ptr[n+1];
        float a0=0.f,a1=0.f,a2=0.f,a3=0.f,a4=0.f,a5=0.f,a6=0.f,a7=0.f;
        int e = beg;
        for (; e+8 <= end; e += 8){
          int2 m0=csr_sw[e+0], m1=csr_sw[e+1], m2=csr_sw[e+2], m3=csr_sw[e+3];
          int2 m4=csr_sw[e+4], m5=csr_sw[e+5], m6=csr_sw[e+6], m7=csr_sw[e+7];
          a0 += hp[(size_t)m0.x*HH+lane]*__int_as_float(m0.y);
          a1 += hp[(size_t)m1.x*HH+lane]*__int_as_float(m1.y);
          a2 += hp[(size_t)m2.x*HH+lane]*__int_as_float(m2.y);
          a3 += hp[(size_t)m3.x*HH+lane]*__int_as_float(m3.y);
          a4 += hp[(size_t)m4.x*HH+lane]*__int_as_float(m4.y);
          a5 += hp[(size_t)m5.x*HH+lane]*__int_as_float(m5.y);
          a6 += hp[(size_t)m6.x*HH+lane]*__int_as_float(m6.y);
          a7 += hp[(size_t)m7.x*HH+lane]*__int_as_float(m7.y);
        }
        for (; e < end; ++e){
          int2 m = csr_sw[e];
          a0 += hp[(size_t)m.x*HH+lane]*__int_as_float(m.y);
        }
        lds[r][lane]    = (((a0+a1)+(a2+a3))+((a4+a5)+(a6+a7))) * id;
        lds[r][64+lane] = hp[(size_t)n*HH + lane];
      } else {
        lds[r][lane] = lds[r][64+lane] = 0.f;
      }
    }
    __syncthreads();

    // ---- Phase B: K=128 GEMM; acc init from gx (bias + x-part) ----
    int cg2 = lane & 15, rg = lane >> 4;
    int j0 = wave*64 + cg2*4;
    float acc[5][4];
    #pragma unroll
    for (int rp = 0; rp < 5; ++rp){
      int n = base + rg + 4*rp;
      if (n < N){
        float4 g4 = *(const float4*)&gx_t[(size_t)n*GG + j0];
        acc[rp][0]=g4.x; acc[rp][1]=g4.y; acc[rp][2]=g4.z; acc[rp][3]=g4.w;
      } else {
        acc[rp][0]=acc[rp][1]=acc[rp][2]=acc[rp][3]=0.f;
      }
    }
    #pragma unroll 4
    for (int k = 0; k < 128; k += 4){
      float4 w0 = *(const float4*)&Wh[(size_t)(k+0)*GG + j0];
      float4 w1 = *(const float4*)&Wh[(size_t)(k+1)*GG + j0];
      float4 w2 = *(const float4*)&Wh[(size_t)(k+2)*GG + j0];
      float4 w3 = *(const float4*)&Wh[(size_t)(k+3)*GG + j0];
      #pragma unroll
      for (int rp = 0; rp < 5; ++rp){
        float4 a = *(const float4*)&lds[rg + 4*rp][k];
        acc[rp][0] += a.x*w0.x + a.y*w1.x + a.z*w2.x + a.w*w3.x;
        acc[rp][1] += a.x*w0.y + a.y*w1.y + a.z*w2.y + a.w*w3.y;
        acc[rp][2] += a.x*w0.z + a.y*w1.z + a.z*w2.z + a.w*w3.z;
        acc[rp][3] += a.x*w0.w + a.y*w1.w + a.z*w2.w + a.w*w3.w;
      }
    }
    __syncthreads();
    #pragma unroll
    for (int rp = 0; rp < 5; ++rp){
      float4 g4; g4.x=acc[rp][0]; g4.y=acc[rp][1]; g4.z=acc[rp][2]; g4.w=acc[rp][3];
      *(float4*)&lds[rg + 4*rp][j0] = g4;    // gates
    }
    __syncthreads();

    // ---- Phase C: cell update ----
    for (int r = wave; r < BRP; r += 4){
      int n = base + r;
      if (n >= N) continue;
      float gi = lds[r][lane], gf = lds[r][64+lane], gg2 = lds[r][128+lane], go = lds[r][192+lane];
      float cn = sigmoidf_(gf)*c[(size_t)n*HH+lane] + sigmoidf_(gi)*tanhf(gg2);
      float hn2 = sigmoidf_(go)*tanhf(cn);
      c[(size_t)n*HH+lane] = cn;
      hn[(size_t)n*HH+lane] = hn2;
      if (t >= store_from) h2s[(size_t)(t-store_from)*N*HH + (size_t)n*HH + lane] = hn2;
    }
    grid.sync();
    float* tmp = hp; hp = hn; hn = tmp;
  }
}

// ============ fallback: per-step h aggregation (one wave per node) ============
__global__ __launch_bounds__(256) void hgather_step(
    const float* __restrict__ h_prev, const int* __restrict__ ptr,
    const int2* __restrict__ csr_sw, const float* __restrict__ invd,
    float* __restrict__ h_agg, int N){
  int wave = threadIdx.x >> 6, lane = threadIdx.x & 63;
  int n = blockIdx.x*4 + wave;
  if (n >= N) return;
  int beg = ptr[n], end = ptr[n+1];
  float a0=0.f,a1=0.f,a2=0.f,a3=0.f,a4=0.f,a5=0.f,a6=0.f,a7=0.f;
  int e = beg;
  for (; e+8 <= end; e += 8){
    int2 m0=csr_sw[e+0], m1=csr_sw[e+1], m2=csr_sw[e+2], m3=csr_sw[e+3];
    int2 m4=csr_sw[e+4], m5=csr_sw[e+5], m6=csr_sw[e+6], m7=csr_sw[e+7];
    a0 += h_prev[(size_t)m0.x*HH+lane]*__int_as_float(m0.y);
    a1 += h_prev[(size_t)m1.x*HH+lane]*__int_as_float(m1.y);
    a2 += h_prev[(size_t)m2.x*HH+lane]*__int_as_float(m2.y);
    a3 += h_prev[(size_t)m3.x*HH+lane]*__int_as_float(m3.y);
    a4 += h_prev[(size_t)m4.x*HH+lane]*__int_as_float(m4.y);
    a5 += h_prev[(size_t)m5.x*HH+lane]*__int_as_float(m5.y);
    a6 += h_prev[(size_t)m6.x*HH+lane]*__int_as_float(m6.y);
    a7 += h_prev[(size_t)m7.x*HH+lane]*__int_as_float(m7.y);
  }
  for (; e < end; ++e){
    int2 m = csr_sw[e];
    a0 += h_prev[(size_t)m.x*HH+lane]*__int_as_float(m.y);
  }
  h_agg[(size_t)n*HH+lane] = (((a0+a1)+(a2+a3))+((a4+a5)+(a6+a7))) * invd[n];
}

// ============ fallback: gates GEMM (K=256) + LSTM cell ============
__global__ __launch_bounds__(256) void gates_cell_step(
    const float* __restrict__ xr_t, const float* __restrict__ xragg_t,
    const float* __restrict__ h_agg,
    const float* __restrict__ h_prev, float* __restrict__ h_next,
    float* __restrict__ c,
    const float* __restrict__ Wr, const float* __restrict__ Wroot,
    const float* __restrict__ b,
    float* __restrict__ h2_store, int N){
  __shared__ float lds[BR][LDW];
  int tid = threadIdx.x, wave = tid >> 6, lane = tid & 63;
  int base = blockIdx.x * BR;
  for (int r = 0; r < BR; ++r){
    int n = base + r;
    int k = tid;
    float v;
    if (n < N){
      if      (k < 64)  v = xragg_t[(size_t)n*HH + k];
      else if (k < 128) v = h_agg  [(size_t)n*HH + (k-64)];
      else if (k < 192) v = xr_t   [(size_t)n*HH + (k-128)];
      else              v = h_prev [(size_t)n*HH + (k-192)];
    } else v = 0.f;
    lds[r][k] = v;
  }
  __syncthreads();
  int cg2 = lane & 15, rg = lane >> 4;
  int j0 = wave*64 + cg2*4;
  float acc[4][4];
  {
    float4 bv = *(const float4*)&b[j0];
    #pragma unroll
    for (int r = 0; r < 4; ++r){ acc[r][0]=bv.x; acc[r][1]=bv.y; acc[r][2]=bv.z; acc[r][3]=bv.w; }
  }
  #pragma unroll 4
  for (int k = 0; k < 128; k += 4){
    float4 w0 = *(const float4*)&Wr[(size_t)(k+0)*GG + j0];
    float4 w1 = *(const float4*)&Wr[(size_t)(k+1)*GG + j0];
    float4 w2 = *(const float4*)&Wr[(size_t)(k+2)*GG + j0];
    float4 w3 = *(const float4*)&Wr[(size_t)(k+3)*GG + j0];
    #pragma unroll
    for (int rp = 0; rp < 4; ++rp){
      float4 a = *(const float4*)&lds[rg + 4*rp][k];
      acc[rp][0] += a.x*w0.x + a.y*w1.x + a.z*w2.x + a.w*w3.x;
      acc[rp][1] += a.x*w0.y + a.y*w1.y + a.z*w2.y + a.w*w3.y;
      acc[rp][2] += a.x*w0.z + a.y*w1.z + a.z*w2.z + a.w*w3.z;
      acc[rp][3] += a.x*w0.w + a.y*w1.w + a.z*w2.w + a.w*w3.w;
    }
  }
  #pragma unroll 4
  for (int k = 0; k < 128; k += 4){
    float4 w0 = *(const float4*)&Wroot[(size_t)(k+0)*GG + j0];
    float4 w1 = *(const float4*)&Wroot[(size_t)(k+1)*GG + j0];
    float4 w2 = *(const float4*)&Wroot[(size_t)(k+2)*GG + j0];
    float4 w3 = *(const float4*)&Wroot[(size_t)(k+3)*GG + j0];
    #pragma unroll
    for (int rp = 0; rp < 4; ++rp){
      float4 a = *(const float4*)&lds[rg + 4*rp][128+k];
      acc[rp][0] += a.x*w0.x + a.y*w1.x + a.z*w2.x + a.w*w3.x;
      acc[rp][1] += a.x*w0.y + a.y*w1.y + a.z*w2.y + a.w*w3.y;
      acc[rp][2] += a.x*w0.z + a.y*w1.z + a.z*w2.z + a.w*w3.z;
      acc[rp][3] += a.x*w0.w + a.y*w1.w + a.z*w2.w + a.w*w3.w;
    }
  }
  __syncthreads();
  #pragma unroll
  for (int rp = 0; rp < 4; ++rp){
    float4 g4; g4.x=acc[rp][0]; g4.y=acc[rp][1]; g4.z=acc[rp][2]; g4.w=acc[rp][3];
    *(float4*)&lds[rg + 4*rp][j0] = g4;
  }
  __syncthreads();
  for (int r = wave; r < BR; r += 4){
    int n = base + r;
    if (n >= N) continue;
    float gi = lds[r][lane], gf = lds[r][64+lane], gg2 = lds[r][128+lane], go = lds[r][192+lane];
    float cn = sigmoidf_(gf)*c[(size_t)n*HH+lane] + sigmoidf_(gi)*tanhf(gg2);
    float hn = sigmoidf_(go)*tanhf(cn);
    c[(size_t)n*HH+lane] = cn;
    h_next[(size_t)n*HH+lane] = hn;
    if (h2_store) h2_store[(size_t)n*HH+lane] = hn;
  }
}

// ================= output head =================
__global__ void out_gemm(const float* __restrict__ xr8, const float* __restrict__ h2s,
                         const float* __restrict__ Wout, const float* __restrict__ bout,
                         float* __restrict__ out, int N){
  int idx = blockIdx.x*blockDim.x + threadIdx.x;
  if (idx >= NF*N*OO) return;
  int o = idx & (OO-1);
  int row = idx >> 3;                     // tt*N + n
  const float* xv = xr8 + (size_t)row*HH;
  const float* hv = h2s + (size_t)row*HH;
  float acc = bout[o];
  #pragma unroll
  for (int k = 0; k < HH; ++k)
    acc += xv[k]*Wout[k*OO+o] + hv[k]*Wout[(HH+k)*OO+o];
  out[idx] = acc;
}

__global__ void copyk(const float* __restrict__ s, float* __restrict__ d, int n){
  int i = blockIdx.x*blockDim.x + threadIdx.x;
  if (i < n) d[i] = s[i];
}

extern "C" void kernel_launch(void* const* d_in, const int* in_sizes, int n_in,
                              void* d_out, int out_size, void* d_ws, size_t ws_size,
                              hipStream_t stream){
  const float* x      = (const float*)d_in[0];
  const int*   ei     = (const int*)  d_in[1];
  const float* ew     = (const float*)d_in[2];
  const float* sWr    = (const float*)d_in[3];
  const float* sWroot = (const float*)d_in[4];
  const float* sb     = (const float*)d_in[5];
  const float* l1Wr   = (const float*)d_in[6];
  const float* l1Wroot= (const float*)d_in[7];
  const float* l1b    = (const float*)d_in[8];
  const float* l2Wr   = (const float*)d_in[9];
  const float* l2Wroot= (const float*)d_in[10];
  const float* l2b    = (const float*)d_in[11];
  const float* Wout   = (const float*)d_in[12];
  const float* bout   = (const float*)d_in[13];

  const int E = in_sizes[2];
  const int N = in_sizes[0] / (TT*FF);
  const int* src = ei;
  const int* dst = ei + E;

  float* out0   = (float*)d_out;              // [4,N,8]
  float* c2out  = out0 + (size_t)NF*N*OO;     // [N,64]
  float* embout = c2out + (size_t)N*HH;       // [12,N,64]

  float* w = (float*)d_ws;
  float* xr     = w;  w += (size_t)TT*N*HH;
  float* xr_agg = w;  w += (size_t)TT*N*HH;
  float* agg_x  = xr_agg;                     // alias: dead before xr_agg written
  float* hA     = w;  w += (size_t)N*HH;
  float* hB     = w;  w += (size_t)N*HH;
  float* cbuf   = w;  w += (size_t)N*HH;
  float* haggb  = w;  w += (size_t)N*HH;      // fallback path only
  float* h2s    = w;  w += (size_t)NF*N*HH;
  float* invd   = w;  w += N;
  int*   cnt    = (int*)w;  w += N;
  int*   fill   = (int*)w;  w += N;
  int*   ptr    = (int*)w;  w += (N+2);       // keep int2 array 8B-aligned
  int2*  csr_sw = (int2*)w; w += (size_t)2*E;
  float* Wxbuf  = w;  w += (size_t)128*GG;    // packed x-part weights (per layer)
  float* Whbuf1 = w;  w += (size_t)128*GG;    // packed h-part weights, layer1
  float* Whbuf2 = w;  w += (size_t)128*GG;    // packed h-part weights, layer2
  float* gx     = w;  w += (size_t)TT*N*GG;   // 245.8 MB, reused per layer

  const size_t ws_need = (size_t)((char*)(w) - (char*)d_ws);

  hipMemsetAsync(cnt,  0, (size_t)N*4, stream);
  hipMemsetAsync(fill, 0, (size_t)N*4, stream);
  hipMemsetAsync(hA,   0, (size_t)N*HH*4, stream);  // h0
  hipMemsetAsync(cbuf, 0, (size_t)N*HH*4, stream);  // c0

  hist_kernel<<<(E+255)/256, 256, 0, stream>>>(dst, cnt, E);
  scan_kernel<<<1, 1024, 0, stream>>>(cnt, ptr, invd, N);
  fill_kernel<<<(E+255)/256, 256, 0, stream>>>(src, dst, ew, ptr, fill, csr_sw, E);

  sage_gather<<<(N+3)/4, 256, 0, stream>>>(x, ptr, csr_sw, invd, agg_x, N);
  sage_gemm<<<((size_t)TT*N*HH+255)/256, 256, 0, stream>>>(x, agg_x, sWr, sWroot, sb,
                                                           embout, xr, N);
  xr_gather<<<(N+3)/4, 256, 0, stream>>>(xr, ptr, csr_sw, invd, xr_agg, N);

  const int ntilesP = (N + BRP - 1) / BRP;   // 1000
  const int Mrows = TT * N;                  // 240000

  // cooperative capacity (host-only queries; graph-capture-safe)
  int dev = 0; hipGetDevice(&dev);
  int numCU = 0;
  hipDeviceGetAttribute(&numCU, hipDeviceAttributeMultiprocessorCount, dev);
  int maxBlkPerCU = 0;
  hipError_t occErr = hipOccupancyMaxActiveBlocksPerMultiprocessor(
      &maxBlkPerCU, (const void*)lstm_layer, 256, 0);
  long capacity = (long)maxBlkPerCU * (long)numCU;

  const bool usePersist = (occErr == hipSuccess) && (capacity >= ntilesP) &&
                          (ws_size >= ws_need);

  if (usePersist){
    // pack h-part weights once
    pack_w<<<128, 256, 0, stream>>>(l1Wr, l1Wroot, 64, Whbuf1);
    pack_w<<<128, 256, 0, stream>>>(l2Wr, l2Wroot, 64, Whbuf2);

    for (int layer = 0; layer < 2; ++layer){
      const float* Wr    = layer ? l2Wr    : l1Wr;
      const float* Wroot = layer ? l2Wroot : l1Wroot;
      const float* bias  = layer ? l2b     : l1b;
      float* Wh          = layer ? Whbuf2  : Whbuf1;
      int store_from     = layer ? (TT-NF) : TT;   // layer2 stores t>=8

      pack_w<<<128, 256, 0, stream>>>(Wr, Wroot, 0, Wxbuf);
      gx_gemm<<<(Mrows+BR-1)/BR, 256, 0, stream>>>(xr_agg, xr, Wxbuf, bias, gx, Mrows);

      const float* a_gx = gx; const float* a_wh = Wh;
      float* a_hA = hA; float* a_hB = hB; float* a_c = cbuf;
      const float* a_invd = invd; const int* a_ptr = ptr; const int2* a_csr = csr_sw;
      float* a_h2s = h2s; int a_N = N; int a_sf = store_from;
      void* args[] = { (void*)&a_gx, (void*)&a_wh, (void*)&a_hA, (void*)&a_hB, (void*)&a_c,
                       (void*)&a_invd, (void*)&a_ptr, (void*)&a_csr,
                       (void*)&a_h2s, (void*)&a_N, (void*)&a_sf };
      hipLaunchCooperativeKernel((const void*)lstm_layer, dim3(ntilesP), dim3(256),
                                 args, 0, stream);
      // TT=12 even -> final h back in hA, so next layer starts from hA. c stays in cbuf.
    }
  } else {
    // fallback: R5-verified split-kernel recurrence (K=256, no gx)
    const int gBlocks = (N+3)/4;
    const int sBlocks = (N+BR-1)/BR;
    float* hp = hA; float* hn = hB;
    for (int t = 0; t < TT; ++t){
      hgather_step<<<gBlocks, 256, 0, stream>>>(hp, ptr, csr_sw, invd, haggb, N);
      gates_cell_step<<<sBlocks, 256, 0, stream>>>(xr + (size_t)t*N*HH, xr_agg + (size_t)t*N*HH,
                                                   haggb, hp, hn, cbuf,
                                                   l1Wr, l1Wroot, l1b, nullptr, N);
      float* tmp = hp; hp = hn; hn = tmp;
    }
    for (int t = 0; t < TT; ++t){
      float* store = (t >= TT-NF) ? (h2s + (size_t)(t-(TT-NF))*N*HH) : nullptr;
      hgather_step<<<gBlocks, 256, 0, stream>>>(hp, ptr, csr_sw, invd, haggb, N);
      gates_cell_step<<<sBlocks, 256, 0, stream>>>(xr + (size_t)t*N*HH, xr_agg + (size_t)t*N*HH,
                                                   haggb, hp, hn, cbuf,
                                                   l2Wr, l2Wroot, l2b, store, N);
      float* tmp = hp; hp = hn; hn = tmp;
    }
  }

  out_gemm<<<((size_t)NF*N*OO+255)/256, 256, 0, stream>>>(xr + (size_t)(TT-NF)*N*HH, h2s,
                                                          Wout, bout, out0, N);
  copyk<<<((size_t)N*HH+255)/256, 256, 0, stream>>>(cbuf, c2out, N*HH);
}

// Round 9
// 2454.957 us; speedup vs baseline: 1.9949x; 1.2599x over previous
//
#include <hip/hip_runtime.h>
#include <math.h>

#define TT 12
#define FF 32
#define HH 64
#define OO 8
#define GG 256   // 4*HH
#define NF 4     // NUM_FUTURE
#define BR 16    // nodes per lstm block
#define LDW 260  // padded LDS row stride (words); rows rg+4r' -> banks {0,4,8,12}
#define KCH 16   // k-rows per staged weight chunk
#define NCH (GG/KCH)

__device__ __forceinline__ float sigmoidf_(float x){ return 1.f/(1.f+expf(-x)); }

// ================= CSR build =================
__global__ void hist_kernel(const int* __restrict__ dst, int* __restrict__ cnt, int E){
  int e = blockIdx.x*blockDim.x + threadIdx.x;
  if (e < E) atomicAdd(&cnt[dst[e]], 1);
}

__global__ __launch_bounds__(1024) void scan_kernel(const int* __restrict__ cnt,
                                                    int* __restrict__ ptr,
                                                    float* __restrict__ invd, int N){
  __shared__ int buf[1024];
  __shared__ int carry;
  if (threadIdx.x == 0) carry = 0;
  __syncthreads();
  for (int base = 0; base < N; base += 1024){
    int i = base + threadIdx.x;
    int v = (i < N) ? cnt[i] : 0;
    buf[threadIdx.x] = v;
    __syncthreads();
    for (int off = 1; off < 1024; off <<= 1){
      int t = (threadIdx.x >= off) ? buf[threadIdx.x - off] : 0;
      __syncthreads();
      buf[threadIdx.x] += t;
      __syncthreads();
    }
    int incl = buf[threadIdx.x];
    if (i < N){
      ptr[i] = carry + incl - v;
      invd[i] = 1.f / fmaxf((float)v, 1.f);
    }
    __syncthreads();
    if (threadIdx.x == 1023){
      carry += incl;
      if (base + 1024 >= N) ptr[N] = carry;
    }
    __syncthreads();
  }
}

__global__ void fill_kernel(const int* __restrict__ src, const int* __restrict__ dst,
                            const float* __restrict__ ew, const int* __restrict__ ptr,
                            int* __restrict__ fill, int2* __restrict__ csr_sw, int E){
  int e = blockIdx.x*blockDim.x + threadIdx.x;
  if (e >= E) return;
  int d = dst[e];
  int pos = ptr[d] + atomicAdd(&fill[d], 1);
  int2 m; m.x = src[e]; m.y = __float_as_int(ew[e]);
  csr_sw[pos] = m;
}

// ====== weight packing: Wpk[256][256] = [Wr(0..127); Wroot(0..127)] ======
__global__ void pack_full(const float* __restrict__ Wr, const float* __restrict__ Wroot,
                          float* __restrict__ out){
  int idx = blockIdx.x*256 + threadIdx.x;
  if (idx >= 256*GG) return;
  int k = idx >> 8, j = idx & (GG-1);
  out[idx] = (k < 128) ? Wr[(size_t)k*GG + j] : Wroot[(size_t)(k-128)*GG + j];
}

// ========== SAGE aggregation: t-inner (6 planes/lane), edge-unroll 2 ==========
__global__ __launch_bounds__(256) void sage_gather(
    const float* __restrict__ x, const int* __restrict__ ptr,
    const int2* __restrict__ csr_sw,
    const float* __restrict__ invd, float* __restrict__ aggx, int N){
  int wave = threadIdx.x >> 6, lane = threadIdx.x & 63;
  int f = lane & 31, tp = lane >> 5;
  int n = blockIdx.x*4 + wave;
  if (n >= N) return;
  int beg = ptr[n], end = ptr[n+1];
  float id = invd[n];
  float acc[TT/2];
  #pragma unroll
  for (int th = 0; th < TT/2; ++th) acc[th] = 0.f;
  const size_t plane = (size_t)N*FF;
  int e = beg;
  for (; e+2 <= end; e += 2){
    int2 m0 = csr_sw[e], m1 = csr_sw[e+1];
    const float* p0 = x + (size_t)m0.x*FF + f + (size_t)tp*plane;
    const float* p1 = x + (size_t)m1.x*FF + f + (size_t)tp*plane;
    float w0 = __int_as_float(m0.y), w1 = __int_as_float(m1.y);
    #pragma unroll
    for (int th = 0; th < TT/2; ++th)
      acc[th] += p0[2*th*plane]*w0 + p1[2*th*plane]*w1;
  }
  for (; e < end; ++e){
    int2 m = csr_sw[e];
    const float* p = x + (size_t)m.x*FF + f + (size_t)tp*plane;
    float wv = __int_as_float(m.y);
    #pragma unroll
    for (int th = 0; th < TT/2; ++th)
      acc[th] += p[2*th*plane]*wv;
  }
  #pragma unroll
  for (int th = 0; th < TT/2; ++th)
    aggx[(size_t)(2*th+tp)*plane + (size_t)n*FF + f] = acc[th] * id;  // pre-normalized
}

// ================= SAGE linear: emb = agg@Wr + x@Wroot + b ; xr = relu =====
__global__ __launch_bounds__(256) void sage_gemm(
    const float* __restrict__ x, const float* __restrict__ agg,
    const float* __restrict__ Wr, const float* __restrict__ Wroot,
    const float* __restrict__ b,
    float* __restrict__ emb, float* __restrict__ xr, int N){
  __shared__ float sWr[FF*HH], sWroot[FF*HH];
  for (int i = threadIdx.x; i < FF*HH; i += 256){ sWr[i] = Wr[i]; sWroot[i] = Wroot[i]; }
  __syncthreads();
  int idx = blockIdx.x*256 + threadIdx.x;
  int row = idx >> 6, hh = idx & (HH-1);
  if (row >= TT*N) return;
  const float* xv = x   + (size_t)row*FF;
  const float* av = agg + (size_t)row*FF;
  float acc = b[hh];
  #pragma unroll
  for (int k = 0; k < FF; ++k)
    acc += av[k]*sWr[k*HH+hh] + xv[k]*sWroot[k*HH+hh];
  emb[(size_t)row*HH + hh] = acc;
  xr[(size_t)row*HH + hh]  = fmaxf(acc, 0.f);
}

// ========== xr aggregation: t-inner (12 acc), edge-unroll 2 ==========
__global__ __launch_bounds__(256) void xr_gather(
    const float* __restrict__ xr, const int* __restrict__ ptr,
    const int2* __restrict__ csr_sw,
    const float* __restrict__ invd, float* __restrict__ xr_agg, int N){
  int wave = threadIdx.x >> 6, lane = threadIdx.x & 63;
  int n = blockIdx.x*4 + wave;
  if (n >= N) return;
  int beg = ptr[n], end = ptr[n+1];
  float id = invd[n];
  float acc[TT];
  #pragma unroll
  for (int t = 0; t < TT; ++t) acc[t] = 0.f;
  const size_t plane = (size_t)N*HH;
  int e = beg;
  for (; e+2 <= end; e += 2){
    int2 m0 = csr_sw[e], m1 = csr_sw[e+1];
    const float* p0 = xr + (size_t)m0.x*HH + lane;
    const float* p1 = xr + (size_t)m1.x*HH + lane;
    float w0 = __int_as_float(m0.y), w1 = __int_as_float(m1.y);
    #pragma unroll
    for (int t = 0; t < TT; ++t)
      acc[t] += p0[t*plane]*w0 + p1[t*plane]*w1;
  }
  for (; e < end; ++e){
    int2 m = csr_sw[e];
    const float* p = xr + (size_t)m.x*HH + lane;
    float wv = __int_as_float(m.y);
    #pragma unroll
    for (int t = 0; t < TT; ++t)
      acc[t] += p[t*plane]*wv;
  }
  #pragma unroll
  for (int t = 0; t < TT; ++t)
    xr_agg[(size_t)t*plane + (size_t)n*HH + lane] = acc[t] * id;  // pre-normalized
}

// ============ fused step: h-gather + LDS-staged gates GEMM + cell ============
// A = [xr_agg | h_agg | xr | h] (K=256); gates = A @ Wpk + bias
// W streamed through 2x16-row LDS chunks (double-buffered, coalesced float4).
__global__ __launch_bounds__(256, 3) void lstm_fused(
    const float* __restrict__ xr_t, const float* __restrict__ xragg_t,
    const float* __restrict__ h_prev, float* __restrict__ h_next,
    float* __restrict__ c, const float* __restrict__ invd,
    const int* __restrict__ ptr, const int2* __restrict__ csr_sw,
    const float* __restrict__ Wpk, const float* __restrict__ bias,
    float* __restrict__ h2_store, int N){
  __shared__ float Albuf[BR][LDW];          // A-tile, reused for gates
  __shared__ float Wbuf[2][KCH][GG];        // 2 x 16KB weight chunks
  int tid = threadIdx.x, wave = tid >> 6, lane = tid & 63;
  int base = blockIdx.x * BR;

  // ---- Phase A: gather h_agg (unroll-8) + stage inputs ----
  for (int r4 = 0; r4 < 4; ++r4){
    int r = wave*4 + r4;
    int n = base + r;
    if (n < N){
      float id = invd[n];
      int beg = ptr[n], end = ptr[n+1];
      float a0=0.f,a1=0.f,a2=0.f,a3=0.f,a4=0.f,a5=0.f,a6=0.f,a7=0.f;
      int e = beg;
      for (; e+8 <= end; e += 8){
        int2 m0=csr_sw[e+0], m1=csr_sw[e+1], m2=csr_sw[e+2], m3=csr_sw[e+3];
        int2 m4=csr_sw[e+4], m5=csr_sw[e+5], m6=csr_sw[e+6], m7=csr_sw[e+7];
        a0 += h_prev[(size_t)m0.x*HH+lane]*__int_as_float(m0.y);
        a1 += h_prev[(size_t)m1.x*HH+lane]*__int_as_float(m1.y);
        a2 += h_prev[(size_t)m2.x*HH+lane]*__int_as_float(m2.y);
        a3 += h_prev[(size_t)m3.x*HH+lane]*__int_as_float(m3.y);
        a4 += h_prev[(size_t)m4.x*HH+lane]*__int_as_float(m4.y);
        a5 += h_prev[(size_t)m5.x*HH+lane]*__int_as_float(m5.y);
        a6 += h_prev[(size_t)m6.x*HH+lane]*__int_as_float(m6.y);
        a7 += h_prev[(size_t)m7.x*HH+lane]*__int_as_float(m7.y);
      }
      for (; e < end; ++e){
        int2 m = csr_sw[e];
        a0 += h_prev[(size_t)m.x*HH+lane]*__int_as_float(m.y);
      }
      Albuf[r][ 64+lane] = (((a0+a1)+(a2+a3))+((a4+a5)+(a6+a7))) * id;
      Albuf[r][    lane] = xragg_t[(size_t)n*HH + lane];
      Albuf[r][128+lane] = xr_t   [(size_t)n*HH + lane];
      Albuf[r][192+lane] = h_prev [(size_t)n*HH + lane];
    } else {
      Albuf[r][lane] = Albuf[r][64+lane] = Albuf[r][128+lane] = Albuf[r][192+lane] = 0.f;
    }
  }
  // prefetch weight chunk 0 (coalesced: lane-contiguous float4)
  #pragma unroll
  for (int q = 0; q < 4; ++q){
    int f4 = q*256 + tid;
    int kk = f4 >> 6, c4 = (f4 & 63) << 2;
    *(float4*)&Wbuf[0][kk][c4] = *(const float4*)&Wpk[(size_t)kk*GG + c4];
  }
  __syncthreads();

  // ---- Phase B: GEMM, W double-buffered through LDS ----
  int cg2 = lane & 15, rg = lane >> 4;
  int j0 = wave*64 + cg2*4;
  float acc[4][4];
  {
    float4 bv = *(const float4*)&bias[j0];
    #pragma unroll
    for (int rp = 0; rp < 4; ++rp){ acc[rp][0]=bv.x; acc[rp][1]=bv.y; acc[rp][2]=bv.z; acc[rp][3]=bv.w; }
  }
  for (int ch = 0; ch < NCH; ++ch){
    int cur = ch & 1;
    if (ch < NCH-1){
      int kbase = (ch+1)*KCH;
      #pragma unroll
      for (int q = 0; q < 4; ++q){
        int f4 = q*256 + tid;
        int kk = f4 >> 6, c4 = (f4 & 63) << 2;
        *(float4*)&Wbuf[cur^1][kk][c4] = *(const float4*)&Wpk[(size_t)(kbase+kk)*GG + c4];
      }
    }
    int kb = ch*KCH;
    #pragma unroll
    for (int kk = 0; kk < KCH; kk += 4){
      float4 w0 = *(const float4*)&Wbuf[cur][kk+0][j0];
      float4 w1 = *(const float4*)&Wbuf[cur][kk+1][j0];
      float4 w2 = *(const float4*)&Wbuf[cur][kk+2][j0];
      float4 w3 = *(const float4*)&Wbuf[cur][kk+3][j0];
      #pragma unroll
      for (int rp = 0; rp < 4; ++rp){
        float4 a = *(const float4*)&Albuf[rg + 4*rp][kb + kk];
        acc[rp][0] += a.x*w0.x + a.y*w1.x + a.z*w2.x + a.w*w3.x;
        acc[rp][1] += a.x*w0.y + a.y*w1.y + a.z*w2.y + a.w*w3.y;
        acc[rp][2] += a.x*w0.z + a.y*w1.z + a.z*w2.z + a.w*w3.z;
        acc[rp][3] += a.x*w0.w + a.y*w1.w + a.z*w2.w + a.w*w3.w;
      }
    }
    __syncthreads();   // writes to Wbuf[cur^1] visible; reads of Wbuf[cur]/Albuf done
  }

  // ---- gates -> LDS (Albuf reuse) ----
  #pragma unroll
  for (int rp = 0; rp < 4; ++rp){
    float4 g4; g4.x=acc[rp][0]; g4.y=acc[rp][1]; g4.z=acc[rp][2]; g4.w=acc[rp][3];
    *(float4*)&Albuf[rg + 4*rp][j0] = g4;
  }
  __syncthreads();

  // ---- Phase C: cell update ----
  for (int r = wave; r < BR; r += 4){
    int n = base + r;
    if (n >= N) continue;
    float gi = Albuf[r][lane], gf = Albuf[r][64+lane], gg2 = Albuf[r][128+lane], go = Albuf[r][192+lane];
    float cn = sigmoidf_(gf)*c[(size_t)n*HH+lane] + sigmoidf_(gi)*tanhf(gg2);
    float hn = sigmoidf_(go)*tanhf(cn);
    c[(size_t)n*HH+lane] = cn;
    h_next[(size_t)n*HH+lane] = hn;
    if (h2_store) h2_store[(size_t)n*HH+lane] = hn;
  }
}

// ================= output head =================
__global__ void out_gemm(const float* __restrict__ xr8, const float* __restrict__ h2s,
                         const float* __restrict__ Wout, const float* __restrict__ bout,
                         float* __restrict__ out, int N){
  int idx = blockIdx.x*blockDim.x + threadIdx.x;
  if (idx >= NF*N*OO) return;
  int o = idx & (OO-1);
  int row = idx >> 3;                     // tt*N + n
  const float* xv = xr8 + (size_t)row*HH;
  const float* hv = h2s + (size_t)row*HH;
  float acc = bout[o];
  #pragma unroll
  for (int k = 0; k < HH; ++k)
    acc += xv[k]*Wout[k*OO+o] + hv[k]*Wout[(HH+k)*OO+o];
  out[idx] = acc;
}

__global__ void copyk(const float* __restrict__ s, float* __restrict__ d, int n){
  int i = blockIdx.x*blockDim.x + threadIdx.x;
  if (i < n) d[i] = s[i];
}

extern "C" void kernel_launch(void* const* d_in, const int* in_sizes, int n_in,
                              void* d_out, int out_size, void* d_ws, size_t ws_size,
                              hipStream_t stream){
  const float* x      = (const float*)d_in[0];
  const int*   ei     = (const int*)  d_in[1];
  const float* ew     = (const float*)d_in[2];
  const float* sWr    = (const float*)d_in[3];
  const float* sWroot = (const float*)d_in[4];
  const float* sb     = (const float*)d_in[5];
  const float* l1Wr   = (const float*)d_in[6];
  const float* l1Wroot= (const float*)d_in[7];
  const float* l1b    = (const float*)d_in[8];
  const float* l2Wr   = (const float*)d_in[9];
  const float* l2Wroot= (const float*)d_in[10];
  const float* l2b    = (const float*)d_in[11];
  const float* Wout   = (const float*)d_in[12];
  const float* bout   = (const float*)d_in[13];

  const int E = in_sizes[2];
  const int N = in_sizes[0] / (TT*FF);
  const int* src = ei;
  const int* dst = ei + E;

  float* out0   = (float*)d_out;              // [4,N,8]
  float* c2out  = out0 + (size_t)NF*N*OO;     // [N,64]
  float* embout = c2out + (size_t)N*HH;       // [12,N,64]

  float* w = (float*)d_ws;
  float* xr     = w;  w += (size_t)TT*N*HH;
  float* xr_agg = w;  w += (size_t)TT*N*HH;
  float* agg_x  = xr_agg;                     // alias: dead before xr_agg written
  float* hA     = w;  w += (size_t)N*HH;
  float* hB     = w;  w += (size_t)N*HH;
  float* cbuf   = w;  w += (size_t)N*HH;
  float* h2s    = w;  w += (size_t)NF*N*HH;
  float* invd   = w;  w += N;
  int*   cnt    = (int*)w;  w += N;
  int*   fill   = (int*)w;  w += N;
  int*   ptr    = (int*)w;  w += (N+2);       // keep int2 array 8B-aligned
  int2*  csr_sw = (int2*)w; w += (size_t)2*E;
  float* Wpk1   = w;  w += (size_t)256*GG;    // packed [Wr;Wroot] layer1
  float* Wpk2   = w;  w += (size_t)256*GG;    // packed [Wr;Wroot] layer2

  hipMemsetAsync(cnt,  0, (size_t)N*4, stream);
  hipMemsetAsync(fill, 0, (size_t)N*4, stream);
  hipMemsetAsync(hA,   0, (size_t)N*HH*4, stream);  // h0
  hipMemsetAsync(cbuf, 0, (size_t)N*HH*4, stream);  // c0

  hist_kernel<<<(E+255)/256, 256, 0, stream>>>(dst, cnt, E);
  scan_kernel<<<1, 1024, 0, stream>>>(cnt, ptr, invd, N);
  fill_kernel<<<(E+255)/256, 256, 0, stream>>>(src, dst, ew, ptr, fill, csr_sw, E);

  pack_full<<<(256*GG+255)/256, 256, 0, stream>>>(l1Wr, l1Wroot, Wpk1);
  pack_full<<<(256*GG+255)/256, 256, 0, stream>>>(l2Wr, l2Wroot, Wpk2);

  sage_gather<<<(N+3)/4, 256, 0, stream>>>(x, ptr, csr_sw, invd, agg_x, N);
  sage_gemm<<<((size_t)TT*N*HH+255)/256, 256, 0, stream>>>(x, agg_x, sWr, sWroot, sb,
                                                           embout, xr, N);
  xr_gather<<<(N+3)/4, 256, 0, stream>>>(xr, ptr, csr_sw, invd, xr_agg, N);

  const int sBlocks = (N+BR-1)/BR;      // 1250
  float* hp = hA; float* hn = hB;
  // LSTM1
  for (int t = 0; t < TT; ++t){
    lstm_fused<<<sBlocks, 256, 0, stream>>>(xr + (size_t)t*N*HH, xr_agg + (size_t)t*N*HH,
                                            hp, hn, cbuf, invd, ptr, csr_sw,
                                            Wpk1, l1b, nullptr, N);
    float* tmp = hp; hp = hn; hn = tmp;
  }
  // LSTM2 (continues from h1[-1], c1); h2 stored for t>=8
  for (int t = 0; t < TT; ++t){
    float* store = (t >= TT-NF) ? (h2s + (size_t)(t-(TT-NF))*N*HH) : nullptr;
    lstm_fused<<<sBlocks, 256, 0, stream>>>(xr + (size_t)t*N*HH, xr_agg + (size_t)t*N*HH,
                                            hp, hn, cbuf, invd, ptr, csr_sw,
                                            Wpk2, l2b, store, N);
    float* tmp = hp; hp = hn; hn = tmp;
  }

  out_gemm<<<((size_t)NF*N*OO+255)/256, 256, 0, stream>>>(xr + (size_t)(TT-NF)*N*HH, h2s,
                                                          Wout, bout, out0, N);
  copyk<<<((size_t)N*HH+255)/256, 256, 0, stream>>>(cbuf, c2out, N*HH);
}

// Round 10
// 1307.132 us; speedup vs baseline: 3.7467x; 1.8781x over previous
//
#include <hip/hip_runtime.h>
#include <math.h>

#define TT 12
#define FF 32
#define HH 64
#define OO 8
#define GG 256   // 4*HH
#define NF 4     // NUM_FUTURE
#define BR 16    // nodes per lstm block

typedef __bf16 bf16x8 __attribute__((ext_vector_type(8)));
typedef float  f32x4  __attribute__((ext_vector_type(4)));

__device__ __forceinline__ float sigmoidf_(float x){ return 1.f/(1.f+expf(-x)); }
__device__ __forceinline__ unsigned short f2bf(float f){   // round-to-nearest-even
  unsigned int u = __float_as_uint(f);
  u += 0x7FFFu + ((u >> 16) & 1u);
  return (unsigned short)(u >> 16);
}

// ================= CSR build =================
__global__ void hist_kernel(const int* __restrict__ dst, int* __restrict__ cnt, int E){
  int e = blockIdx.x*blockDim.x + threadIdx.x;
  if (e < E) atomicAdd(&cnt[dst[e]], 1);
}

__global__ __launch_bounds__(1024) void scan_kernel(const int* __restrict__ cnt,
                                                    int* __restrict__ ptr,
                                                    float* __restrict__ invd, int N){
  __shared__ int buf[1024];
  __shared__ int carry;
  if (threadIdx.x == 0) carry = 0;
  __syncthreads();
  for (int base = 0; base < N; base += 1024){
    int i = base + threadIdx.x;
    int v = (i < N) ? cnt[i] : 0;
    buf[threadIdx.x] = v;
    __syncthreads();
    for (int off = 1; off < 1024; off <<= 1){
      int t = (threadIdx.x >= off) ? buf[threadIdx.x - off] : 0;
      __syncthreads();
      buf[threadIdx.x] += t;
      __syncthreads();
    }
    int incl = buf[threadIdx.x];
    if (i < N){
      ptr[i] = carry + incl - v;
      invd[i] = 1.f / fmaxf((float)v, 1.f);
    }
    __syncthreads();
    if (threadIdx.x == 1023){
      carry += incl;
      if (base + 1024 >= N) ptr[N] = carry;
    }
    __syncthreads();
  }
}

__global__ void fill_kernel(const int* __restrict__ src, const int* __restrict__ dst,
                            const float* __restrict__ ew, const int* __restrict__ ptr,
                            int* __restrict__ fill, int2* __restrict__ csr_sw, int E){
  int e = blockIdx.x*blockDim.x + threadIdx.x;
  if (e >= E) return;
  int d = dst[e];
  int pos = ptr[d] + atomicAdd(&fill[d], 1);
  int2 m; m.x = src[e]; m.y = __float_as_int(ew[e]);
  csr_sw[pos] = m;
}

// ====== MFMA B-fragment weight packing (bf16) ======
// Wfrag[((jt*8+ks)*64+l)*8+e] = Wpk[ks*32+(l>>4)*8+e][jt*16+(l&15)]
// where Wpk rows = [Wr(0..127); Wroot(0..127)]
__global__ void pack_wfrag(const float* __restrict__ Wr, const float* __restrict__ Wroot,
                           unsigned short* __restrict__ Wfrag){
  int idx = blockIdx.x*256 + threadIdx.x;
  if (idx >= 16*8*64*8) return;
  int e  = idx & 7;
  int l  = (idx >> 3) & 63;
  int ks = (idx >> 9) & 7;
  int jt = idx >> 12;
  int k = ks*32 + (l>>4)*8 + e;
  int j = jt*16 + (l&15);
  float v = (k < 128) ? Wr[(size_t)k*GG + j] : Wroot[(size_t)(k-128)*GG + j];
  Wfrag[idx] = f2bf(v);
}

// ========== SAGE aggregation: t-inner (6 planes/lane), edge-unroll 2 ==========
__global__ __launch_bounds__(256) void sage_gather(
    const float* __restrict__ x, const int* __restrict__ ptr,
    const int2* __restrict__ csr_sw,
    const float* __restrict__ invd, float* __restrict__ aggx, int N){
  int wave = threadIdx.x >> 6, lane = threadIdx.x & 63;
  int f = lane & 31, tp = lane >> 5;
  int n = blockIdx.x*4 + wave;
  if (n >= N) return;
  int beg = ptr[n], end = ptr[n+1];
  float id = invd[n];
  float acc[TT/2];
  #pragma unroll
  for (int th = 0; th < TT/2; ++th) acc[th] = 0.f;
  const size_t plane = (size_t)N*FF;
  int e = beg;
  for (; e+2 <= end; e += 2){
    int2 m0 = csr_sw[e], m1 = csr_sw[e+1];
    const float* p0 = x + (size_t)m0.x*FF + f + (size_t)tp*plane;
    const float* p1 = x + (size_t)m1.x*FF + f + (size_t)tp*plane;
    float w0 = __int_as_float(m0.y), w1 = __int_as_float(m1.y);
    #pragma unroll
    for (int th = 0; th < TT/2; ++th)
      acc[th] += p0[2*th*plane]*w0 + p1[2*th*plane]*w1;
  }
  for (; e < end; ++e){
    int2 m = csr_sw[e];
    const float* p = x + (size_t)m.x*FF + f + (size_t)tp*plane;
    float wv = __int_as_float(m.y);
    #pragma unroll
    for (int th = 0; th < TT/2; ++th)
      acc[th] += p[2*th*plane]*wv;
  }
  #pragma unroll
  for (int th = 0; th < TT/2; ++th)
    aggx[(size_t)(2*th+tp)*plane + (size_t)n*FF + f] = acc[th] * id;  // pre-normalized
}

// ================= SAGE linear: emb = agg@Wr + x@Wroot + b ; xr = relu =====
__global__ __launch_bounds__(256) void sage_gemm(
    const float* __restrict__ x, const float* __restrict__ agg,
    const float* __restrict__ Wr, const float* __restrict__ Wroot,
    const float* __restrict__ b,
    float* __restrict__ emb, float* __restrict__ xr, int N){
  __shared__ float sWr[FF*HH], sWroot[FF*HH];
  for (int i = threadIdx.x; i < FF*HH; i += 256){ sWr[i] = Wr[i]; sWroot[i] = Wroot[i]; }
  __syncthreads();
  int idx = blockIdx.x*256 + threadIdx.x;
  int row = idx >> 6, hh = idx & (HH-1);
  if (row >= TT*N) return;
  const float* xv = x   + (size_t)row*FF;
  const float* av = agg + (size_t)row*FF;
  float acc = b[hh];
  #pragma unroll
  for (int k = 0; k < FF; ++k)
    acc += av[k]*sWr[k*HH+hh] + xv[k]*sWroot[k*HH+hh];
  emb[(size_t)row*HH + hh] = acc;
  xr[(size_t)row*HH + hh]  = fmaxf(acc, 0.f);
}

// ========== xr aggregation: t-inner (12 acc), edge-unroll 2 ==========
__global__ __launch_bounds__(256) void xr_gather(
    const float* __restrict__ xr, const int* __restrict__ ptr,
    const int2* __restrict__ csr_sw,
    const float* __restrict__ invd, float* __restrict__ xr_agg, int N){
  int wave = threadIdx.x >> 6, lane = threadIdx.x & 63;
  int n = blockIdx.x*4 + wave;
  if (n >= N) return;
  int beg = ptr[n], end = ptr[n+1];
  float id = invd[n];
  float acc[TT];
  #pragma unroll
  for (int t = 0; t < TT; ++t) acc[t] = 0.f;
  const size_t plane = (size_t)N*HH;
  int e = beg;
  for (; e+2 <= end; e += 2){
    int2 m0 = csr_sw[e], m1 = csr_sw[e+1];
    const float* p0 = xr + (size_t)m0.x*HH + lane;
    const float* p1 = xr + (size_t)m1.x*HH + lane;
    float w0 = __int_as_float(m0.y), w1 = __int_as_float(m1.y);
    #pragma unroll
    for (int t = 0; t < TT; ++t)
      acc[t] += p0[t*plane]*w0 + p1[t*plane]*w1;
  }
  for (; e < end; ++e){
    int2 m = csr_sw[e];
    const float* p = xr + (size_t)m.x*HH + lane;
    float wv = __int_as_float(m.y);
    #pragma unroll
    for (int t = 0; t < TT; ++t)
      acc[t] += p[t*plane]*wv;
  }
  #pragma unroll
  for (int t = 0; t < TT; ++t)
    xr_agg[(size_t)t*plane + (size_t)n*HH + lane] = acc[t] * id;  // pre-normalized
}

// ============ fused step: h-gather + bf16 MFMA gates GEMM + cell ============
// A(bf16) = [xr_agg | h_agg | xr | h] (16 x K=256); gates = A @ W + bias
// W consumed as pre-packed B-fragments straight from global (L2-hot, 128KB).
__global__ __launch_bounds__(256) void lstm_mfma(
    const float* __restrict__ xr_t, const float* __restrict__ xragg_t,
    const float* __restrict__ h_prev, float* __restrict__ h_next,
    float* __restrict__ c, const float* __restrict__ invd,
    const int* __restrict__ ptr, const int2* __restrict__ csr_sw,
    const unsigned short* __restrict__ Wfrag, const float* __restrict__ bias,
    float* __restrict__ h2_store, int N){
  __shared__ __align__(16) unsigned short Albuf[BR][264];  // bf16 A-tile, padded
  __shared__ float gbuf[BR][260];                          // fp32 gates
  int tid = threadIdx.x, wave = tid >> 6, lane = tid & 63;
  int base = blockIdx.x * BR;

  // ---- Phase A: gather h_agg (unroll-8) + stage bf16 A-tile ----
  for (int r4 = 0; r4 < 4; ++r4){
    int r = wave*4 + r4;
    int n = base + r;
    if (n < N){
      float id = invd[n];
      int beg = ptr[n], end = ptr[n+1];
      float a0=0.f,a1=0.f,a2=0.f,a3=0.f,a4=0.f,a5=0.f,a6=0.f,a7=0.f;
      int e = beg;
      for (; e+8 <= end; e += 8){
        int2 m0=csr_sw[e+0], m1=csr_sw[e+1], m2=csr_sw[e+2], m3=csr_sw[e+3];
        int2 m4=csr_sw[e+4], m5=csr_sw[e+5], m6=csr_sw[e+6], m7=csr_sw[e+7];
        a0 += h_prev[(size_t)m0.x*HH+lane]*__int_as_float(m0.y);
        a1 += h_prev[(size_t)m1.x*HH+lane]*__int_as_float(m1.y);
        a2 += h_prev[(size_t)m2.x*HH+lane]*__int_as_float(m2.y);
        a3 += h_prev[(size_t)m3.x*HH+lane]*__int_as_float(m3.y);
        a4 += h_prev[(size_t)m4.x*HH+lane]*__int_as_float(m4.y);
        a5 += h_prev[(size_t)m5.x*HH+lane]*__int_as_float(m5.y);
        a6 += h_prev[(size_t)m6.x*HH+lane]*__int_as_float(m6.y);
        a7 += h_prev[(size_t)m7.x*HH+lane]*__int_as_float(m7.y);
      }
      for (; e < end; ++e){
        int2 m = csr_sw[e];
        a0 += h_prev[(size_t)m.x*HH+lane]*__int_as_float(m.y);
      }
      float hag = (((a0+a1)+(a2+a3))+((a4+a5)+(a6+a7))) * id;
      Albuf[r][    lane] = f2bf(xragg_t[(size_t)n*HH + lane]);
      Albuf[r][ 64+lane] = f2bf(hag);
      Albuf[r][128+lane] = f2bf(xr_t   [(size_t)n*HH + lane]);
      Albuf[r][192+lane] = f2bf(h_prev [(size_t)n*HH + lane]);
    } else {
      Albuf[r][lane] = Albuf[r][64+lane] = Albuf[r][128+lane] = Albuf[r][192+lane] = 0;
    }
  }
  __syncthreads();

  // ---- Phase B: MFMA; wave owns cols [64w,64w+64) = 4 tiles of 16 ----
  int l15 = lane & 15, l4 = lane >> 4;
  f32x4 acc[4];
  #pragma unroll
  for (int jtl = 0; jtl < 4; ++jtl){
    float bv = bias[wave*64 + jtl*16 + l15];
    acc[jtl][0]=bv; acc[jtl][1]=bv; acc[jtl][2]=bv; acc[jtl][3]=bv;
  }
  #pragma unroll
  for (int ks = 0; ks < 8; ++ks){
    bf16x8 af = *(const bf16x8*)&Albuf[l15][ks*32 + l4*8];
    #pragma unroll
    for (int jtl = 0; jtl < 4; ++jtl){
      int jt = wave*4 + jtl;
      bf16x8 bf = *(const bf16x8*)&Wfrag[(size_t)(((jt*8 + ks)*64) + lane) * 8];
      acc[jtl] = __builtin_amdgcn_mfma_f32_16x16x32_bf16(af, bf, acc[jtl], 0, 0, 0);
    }
  }
  // gates -> LDS: D layout col=lane&15, row=(lane>>4)*4+i  (m89-verified)
  #pragma unroll
  for (int jtl = 0; jtl < 4; ++jtl){
    int col = wave*64 + jtl*16 + l15;
    #pragma unroll
    for (int i = 0; i < 4; ++i)
      gbuf[l4*4 + i][col] = acc[jtl][i];
  }
  __syncthreads();

  // ---- Phase C: cell update ----
  for (int r = wave; r < BR; r += 4){
    int n = base + r;
    if (n >= N) continue;
    float gi = gbuf[r][lane], gf = gbuf[r][64+lane], gg2 = gbuf[r][128+lane], go = gbuf[r][192+lane];
    float cn = sigmoidf_(gf)*c[(size_t)n*HH+lane] + sigmoidf_(gi)*tanhf(gg2);
    float hn = sigmoidf_(go)*tanhf(cn);
    c[(size_t)n*HH+lane] = cn;
    h_next[(size_t)n*HH+lane] = hn;
    if (h2_store) h2_store[(size_t)n*HH+lane] = hn;
  }
}

// ================= output head =================
__global__ void out_gemm(const float* __restrict__ xr8, const float* __restrict__ h2s,
                         const float* __restrict__ Wout, const float* __restrict__ bout,
                         float* __restrict__ out, int N){
  int idx = blockIdx.x*blockDim.x + threadIdx.x;
  if (idx >= NF*N*OO) return;
  int o = idx & (OO-1);
  int row = idx >> 3;                     // tt*N + n
  const float* xv = xr8 + (size_t)row*HH;
  const float* hv = h2s + (size_t)row*HH;
  float acc = bout[o];
  #pragma unroll
  for (int k = 0; k < HH; ++k)
    acc += xv[k]*Wout[k*OO+o] + hv[k]*Wout[(HH+k)*OO+o];
  out[idx] = acc;
}

__global__ void copyk(const float* __restrict__ s, float* __restrict__ d, int n){
  int i = blockIdx.x*blockDim.x + threadIdx.x;
  if (i < n) d[i] = s[i];
}

extern "C" void kernel_launch(void* const* d_in, const int* in_sizes, int n_in,
                              void* d_out, int out_size, void* d_ws, size_t ws_size,
                              hipStream_t stream){
  const float* x      = (const float*)d_in[0];
  const int*   ei     = (const int*)  d_in[1];
  const float* ew     = (const float*)d_in[2];
  const float* sWr    = (const float*)d_in[3];
  const float* sWroot = (const float*)d_in[4];
  const float* sb     = (const float*)d_in[5];
  const float* l1Wr   = (const float*)d_in[6];
  const float* l1Wroot= (const float*)d_in[7];
  const float* l1b    = (const float*)d_in[8];
  const float* l2Wr   = (const float*)d_in[9];
  const float* l2Wroot= (const float*)d_in[10];
  const float* l2b    = (const float*)d_in[11];
  const float* Wout   = (const float*)d_in[12];
  const float* bout   = (const float*)d_in[13];

  const int E = in_sizes[2];
  const int N = in_sizes[0] / (TT*FF);
  const int* src = ei;
  const int* dst = ei + E;

  float* out0   = (float*)d_out;              // [4,N,8]
  float* c2out  = out0 + (size_t)NF*N*OO;     // [N,64]
  float* embout = c2out + (size_t)N*HH;       // [12,N,64]

  float* w = (float*)d_ws;
  float* xr     = w;  w += (size_t)TT*N*HH;
  float* xr_agg = w;  w += (size_t)TT*N*HH;
  float* agg_x  = xr_agg;                     // alias: dead before xr_agg written
  float* hA     = w;  w += (size_t)N*HH;
  float* hB     = w;  w += (size_t)N*HH;
  float* cbuf   = w;  w += (size_t)N*HH;
  float* h2s    = w;  w += (size_t)NF*N*HH;
  float* invd   = w;  w += N;
  int*   cnt    = (int*)w;  w += N;
  int*   fill   = (int*)w;  w += N;
  int*   ptr    = (int*)w;  w += (N+2);       // keep int2 array 8B-aligned
  int2*  csr_sw = (int2*)w; w += (size_t)2*E;
  unsigned short* Wf1 = (unsigned short*)w; w += (size_t)16*8*64*8/2;  // 65536 bf16
  unsigned short* Wf2 = (unsigned short*)w; w += (size_t)16*8*64*8/2;

  hipMemsetAsync(cnt,  0, (size_t)N*4, stream);
  hipMemsetAsync(fill, 0, (size_t)N*4, stream);
  hipMemsetAsync(hA,   0, (size_t)N*HH*4, stream);  // h0
  hipMemsetAsync(cbuf, 0, (size_t)N*HH*4, stream);  // c0

  hist_kernel<<<(E+255)/256, 256, 0, stream>>>(dst, cnt, E);
  scan_kernel<<<1, 1024, 0, stream>>>(cnt, ptr, invd, N);
  fill_kernel<<<(E+255)/256, 256, 0, stream>>>(src, dst, ew, ptr, fill, csr_sw, E);

  pack_wfrag<<<(16*8*64*8+255)/256, 256, 0, stream>>>(l1Wr, l1Wroot, Wf1);
  pack_wfrag<<<(16*8*64*8+255)/256, 256, 0, stream>>>(l2Wr, l2Wroot, Wf2);

  sage_gather<<<(N+3)/4, 256, 0, stream>>>(x, ptr, csr_sw, invd, agg_x, N);
  sage_gemm<<<((size_t)TT*N*HH+255)/256, 256, 0, stream>>>(x, agg_x, sWr, sWroot, sb,
                                                           embout, xr, N);
  xr_gather<<<(N+3)/4, 256, 0, stream>>>(xr, ptr, csr_sw, invd, xr_agg, N);

  const int sBlocks = (N+BR-1)/BR;      // 1250
  float* hp = hA; float* hn = hB;
  // LSTM1
  for (int t = 0; t < TT; ++t){
    lstm_mfma<<<sBlocks, 256, 0, stream>>>(xr + (size_t)t*N*HH, xr_agg + (size_t)t*N*HH,
                                           hp, hn, cbuf, invd, ptr, csr_sw,
                                           Wf1, l1b, nullptr, N);
    float* tmp = hp; hp = hn; hn = tmp;
  }
  // LSTM2 (continues from h1[-1], c1); h2 stored for t>=8
  for (int t = 0; t < TT; ++t){
    float* store = (t >= TT-NF) ? (h2s + (size_t)(t-(TT-NF))*N*HH) : nullptr;
    lstm_mfma<<<sBlocks, 256, 0, stream>>>(xr + (size_t)t*N*HH, xr_agg + (size_t)t*N*HH,
                                           hp, hn, cbuf, invd, ptr, csr_sw,
                                           Wf2, l2b, store, N);
    float* tmp = hp; hp = hn; hn = tmp;
  }

  out_gemm<<<((size_t)NF*N*OO+255)/256, 256, 0, stream>>>(xr + (size_t)(TT-NF)*N*HH, h2s,
                                                          Wout, bout, out0, N);
  copyk<<<((size_t)N*HH+255)/256, 256, 0, stream>>>(cbuf, c2out, N*HH);
}

// Round 11
// 1266.294 us; speedup vs baseline: 3.8675x; 1.0323x over previous
//
#include <hip/hip_runtime.h>
#include <math.h>

#define TT 12
#define FF 32
#define HH 64
#define OO 8
#define GG 256   // 4*HH
#define NF 4     // NUM_FUTURE
#define BR 16    // nodes per lstm block

typedef __bf16 bf16x8 __attribute__((ext_vector_type(8)));
typedef float  f32x4  __attribute__((ext_vector_type(4)));

__device__ __forceinline__ float sigmoidf_(float x){ return 1.f/(1.f+expf(-x)); }
__device__ __forceinline__ unsigned short f2bf(float f){   // round-to-nearest-even
  unsigned int u = __float_as_uint(f);
  u += 0x7FFFu + ((u >> 16) & 1u);
  return (unsigned short)(u >> 16);
}
__device__ __forceinline__ float bf2f(unsigned short b){
  return __uint_as_float(((unsigned int)b) << 16);
}

// ================= CSR build =================
__global__ void hist_kernel(const int* __restrict__ dst, int* __restrict__ cnt, int E){
  int e = blockIdx.x*blockDim.x + threadIdx.x;
  if (e < E) atomicAdd(&cnt[dst[e]], 1);
}

__global__ __launch_bounds__(1024) void scan_kernel(const int* __restrict__ cnt,
                                                    int* __restrict__ ptr,
                                                    float* __restrict__ invd, int N){
  __shared__ int buf[1024];
  __shared__ int carry;
  if (threadIdx.x == 0) carry = 0;
  __syncthreads();
  for (int base = 0; base < N; base += 1024){
    int i = base + threadIdx.x;
    int v = (i < N) ? cnt[i] : 0;
    buf[threadIdx.x] = v;
    __syncthreads();
    for (int off = 1; off < 1024; off <<= 1){
      int t = (threadIdx.x >= off) ? buf[threadIdx.x - off] : 0;
      __syncthreads();
      buf[threadIdx.x] += t;
      __syncthreads();
    }
    int incl = buf[threadIdx.x];
    if (i < N){
      ptr[i] = carry + incl - v;
      invd[i] = 1.f / fmaxf((float)v, 1.f);
    }
    __syncthreads();
    if (threadIdx.x == 1023){
      carry += incl;
      if (base + 1024 >= N) ptr[N] = carry;
    }
    __syncthreads();
  }
}

__global__ void fill_kernel(const int* __restrict__ src, const int* __restrict__ dst,
                            const float* __restrict__ ew, const int* __restrict__ ptr,
                            int* __restrict__ fill, int2* __restrict__ csr_sw, int E){
  int e = blockIdx.x*blockDim.x + threadIdx.x;
  if (e >= E) return;
  int d = dst[e];
  int pos = ptr[d] + atomicAdd(&fill[d], 1);
  int2 m; m.x = src[e]; m.y = __float_as_int(ew[e]);
  csr_sw[pos] = m;
}

// ====== fp32 -> bf16 bulk convert ======
__global__ void bf16_conv(const float* __restrict__ in, unsigned short* __restrict__ out, int n){
  int i = blockIdx.x*blockDim.x + threadIdx.x;
  if (i < n) out[i] = f2bf(in[i]);
}

// ====== MFMA B-fragment weight packing (bf16) ======
__global__ void pack_wfrag(const float* __restrict__ Wr, const float* __restrict__ Wroot,
                           unsigned short* __restrict__ Wfrag){
  int idx = blockIdx.x*256 + threadIdx.x;
  if (idx >= 16*8*64*8) return;
  int e  = idx & 7;
  int l  = (idx >> 3) & 63;
  int ks = (idx >> 9) & 7;
  int jt = idx >> 12;
  int k = ks*32 + (l>>4)*8 + e;
  int j = jt*16 + (l&15);
  float v = (k < 128) ? Wr[(size_t)k*GG + j] : Wroot[(size_t)(k-128)*GG + j];
  Wfrag[idx] = f2bf(v);
}

// ========== SAGE aggregation (bf16 x): t-inner, edge-unroll 2 ==========
__global__ __launch_bounds__(256) void sage_gather(
    const unsigned short* __restrict__ xb, const int* __restrict__ ptr,
    const int2* __restrict__ csr_sw,
    const float* __restrict__ invd, float* __restrict__ aggx, int N){
  int wave = threadIdx.x >> 6, lane = threadIdx.x & 63;
  int f = lane & 31, tp = lane >> 5;
  int n = blockIdx.x*4 + wave;
  if (n >= N) return;
  int beg = ptr[n], end = ptr[n+1];
  float id = invd[n];
  float acc[TT/2];
  #pragma unroll
  for (int th = 0; th < TT/2; ++th) acc[th] = 0.f;
  const size_t plane = (size_t)N*FF;
  int e = beg;
  for (; e+2 <= end; e += 2){
    int2 m0 = csr_sw[e], m1 = csr_sw[e+1];
    const unsigned short* p0 = xb + (size_t)m0.x*FF + f + (size_t)tp*plane;
    const unsigned short* p1 = xb + (size_t)m1.x*FF + f + (size_t)tp*plane;
    float w0 = __int_as_float(m0.y), w1 = __int_as_float(m1.y);
    #pragma unroll
    for (int th = 0; th < TT/2; ++th)
      acc[th] += bf2f(p0[2*th*plane])*w0 + bf2f(p1[2*th*plane])*w1;
  }
  for (; e < end; ++e){
    int2 m = csr_sw[e];
    const unsigned short* p = xb + (size_t)m.x*FF + f + (size_t)tp*plane;
    float wv = __int_as_float(m.y);
    #pragma unroll
    for (int th = 0; th < TT/2; ++th)
      acc[th] += bf2f(p[2*th*plane])*wv;
  }
  #pragma unroll
  for (int th = 0; th < TT/2; ++th)
    aggx[(size_t)(2*th+tp)*plane + (size_t)n*FF + f] = acc[th] * id;  // pre-normalized
}

// ====== SAGE linear: emb(fp32 out) = agg@Wr + x@Wroot + b ; xrb = bf16 relu ======
__global__ __launch_bounds__(256) void sage_gemm(
    const float* __restrict__ x, const float* __restrict__ agg,
    const float* __restrict__ Wr, const float* __restrict__ Wroot,
    const float* __restrict__ b,
    float* __restrict__ emb, unsigned short* __restrict__ xrb, int N){
  __shared__ float sWr[FF*HH], sWroot[FF*HH];
  for (int i = threadIdx.x; i < FF*HH; i += 256){ sWr[i] = Wr[i]; sWroot[i] = Wroot[i]; }
  __syncthreads();
  int idx = blockIdx.x*256 + threadIdx.x;
  int row = idx >> 6, hh = idx & (HH-1);
  if (row >= TT*N) return;
  const float* xv = x   + (size_t)row*FF;
  const float* av = agg + (size_t)row*FF;
  float acc = b[hh];
  #pragma unroll
  for (int k = 0; k < FF; ++k)
    acc += av[k]*sWr[k*HH+hh] + xv[k]*sWroot[k*HH+hh];
  emb[(size_t)row*HH + hh] = acc;
  xrb[(size_t)row*HH + hh] = f2bf(fmaxf(acc, 0.f));
}

// ========== xr aggregation (bf16 in/out): t-inner (12 acc), edge-unroll 2 ==========
__global__ __launch_bounds__(256) void xr_gather(
    const unsigned short* __restrict__ xrb, const int* __restrict__ ptr,
    const int2* __restrict__ csr_sw,
    const float* __restrict__ invd, unsigned short* __restrict__ xr_aggb, int N){
  int wave = threadIdx.x >> 6, lane = threadIdx.x & 63;
  int n = blockIdx.x*4 + wave;
  if (n >= N) return;
  int beg = ptr[n], end = ptr[n+1];
  float id = invd[n];
  float acc[TT];
  #pragma unroll
  for (int t = 0; t < TT; ++t) acc[t] = 0.f;
  const size_t plane = (size_t)N*HH;
  int e = beg;
  for (; e+2 <= end; e += 2){
    int2 m0 = csr_sw[e], m1 = csr_sw[e+1];
    const unsigned short* p0 = xrb + (size_t)m0.x*HH + lane;
    const unsigned short* p1 = xrb + (size_t)m1.x*HH + lane;
    float w0 = __int_as_float(m0.y), w1 = __int_as_float(m1.y);
    #pragma unroll
    for (int t = 0; t < TT; ++t)
      acc[t] += bf2f(p0[t*plane])*w0 + bf2f(p1[t*plane])*w1;
  }
  for (; e < end; ++e){
    int2 m = csr_sw[e];
    const unsigned short* p = xrb + (size_t)m.x*HH + lane;
    float wv = __int_as_float(m.y);
    #pragma unroll
    for (int t = 0; t < TT; ++t)
      acc[t] += bf2f(p[t*plane])*wv;
  }
  #pragma unroll
  for (int t = 0; t < TT; ++t)
    xr_aggb[(size_t)t*plane + (size_t)n*HH + lane] = f2bf(acc[t] * id);  // pre-normalized
}

// ============ fused step: bf16 h-gather + bf16 MFMA gates GEMM + cell ============
__global__ __launch_bounds__(256) void lstm_mfma(
    const unsigned short* __restrict__ xrb_t, const unsigned short* __restrict__ xraggb_t,
    const unsigned short* __restrict__ h_prev, unsigned short* __restrict__ h_next,
    float* __restrict__ c, const float* __restrict__ invd,
    const int* __restrict__ ptr, const int2* __restrict__ csr_sw,
    const unsigned short* __restrict__ Wfrag, const float* __restrict__ bias,
    unsigned short* __restrict__ h2_store, int N){
  __shared__ __align__(16) unsigned short Albuf[BR][264];  // bf16 A-tile, padded
  __shared__ float gbuf[BR][260];                          // fp32 gates
  int tid = threadIdx.x, wave = tid >> 6, lane = tid & 63;
  int base = blockIdx.x * BR;

  // ---- Phase A: gather h_agg (unroll-8) + stage bf16 A-tile ----
  for (int r4 = 0; r4 < 4; ++r4){
    int r = wave*4 + r4;
    int n = base + r;
    if (n < N){
      float id = invd[n];
      int beg = ptr[n], end = ptr[n+1];
      float a0=0.f,a1=0.f,a2=0.f,a3=0.f,a4=0.f,a5=0.f,a6=0.f,a7=0.f;
      int e = beg;
      for (; e+8 <= end; e += 8){
        int2 m0=csr_sw[e+0], m1=csr_sw[e+1], m2=csr_sw[e+2], m3=csr_sw[e+3];
        int2 m4=csr_sw[e+4], m5=csr_sw[e+5], m6=csr_sw[e+6], m7=csr_sw[e+7];
        a0 += bf2f(h_prev[(size_t)m0.x*HH+lane])*__int_as_float(m0.y);
        a1 += bf2f(h_prev[(size_t)m1.x*HH+lane])*__int_as_float(m1.y);
        a2 += bf2f(h_prev[(size_t)m2.x*HH+lane])*__int_as_float(m2.y);
        a3 += bf2f(h_prev[(size_t)m3.x*HH+lane])*__int_as_float(m3.y);
        a4 += bf2f(h_prev[(size_t)m4.x*HH+lane])*__int_as_float(m4.y);
        a5 += bf2f(h_prev[(size_t)m5.x*HH+lane])*__int_as_float(m5.y);
        a6 += bf2f(h_prev[(size_t)m6.x*HH+lane])*__int_as_float(m6.y);
        a7 += bf2f(h_prev[(size_t)m7.x*HH+lane])*__int_as_float(m7.y);
      }
      for (; e < end; ++e){
        int2 m = csr_sw[e];
        a0 += bf2f(h_prev[(size_t)m.x*HH+lane])*__int_as_float(m.y);
      }
      float hag = (((a0+a1)+(a2+a3))+((a4+a5)+(a6+a7))) * id;
      Albuf[r][    lane] = xraggb_t[(size_t)n*HH + lane];
      Albuf[r][ 64+lane] = f2bf(hag);
      Albuf[r][128+lane] = xrb_t [(size_t)n*HH + lane];
      Albuf[r][192+lane] = h_prev[(size_t)n*HH + lane];
    } else {
      Albuf[r][lane] = Albuf[r][64+lane] = Albuf[r][128+lane] = Albuf[r][192+lane] = 0;
    }
  }
  __syncthreads();

  // ---- Phase B: MFMA; wave owns cols [64w,64w+64) = 4 tiles of 16 ----
  int l15 = lane & 15, l4 = lane >> 4;
  f32x4 acc[4];
  #pragma unroll
  for (int jtl = 0; jtl < 4; ++jtl){
    float bv = bias[wave*64 + jtl*16 + l15];
    acc[jtl][0]=bv; acc[jtl][1]=bv; acc[jtl][2]=bv; acc[jtl][3]=bv;
  }
  #pragma unroll
  for (int ks = 0; ks < 8; ++ks){
    bf16x8 af = *(const bf16x8*)&Albuf[l15][ks*32 + l4*8];
    #pragma unroll
    for (int jtl = 0; jtl < 4; ++jtl){
      int jt = wave*4 + jtl;
      bf16x8 bf = *(const bf16x8*)&Wfrag[(size_t)(((jt*8 + ks)*64) + lane) * 8];
      acc[jtl] = __builtin_amdgcn_mfma_f32_16x16x32_bf16(af, bf, acc[jtl], 0, 0, 0);
    }
  }
  // gates -> LDS: D layout col=lane&15, row=(lane>>4)*4+i  (m89-verified)
  #pragma unroll
  for (int jtl = 0; jtl < 4; ++jtl){
    int col = wave*64 + jtl*16 + l15;
    #pragma unroll
    for (int i = 0; i < 4; ++i)
      gbuf[l4*4 + i][col] = acc[jtl][i];
  }
  __syncthreads();

  // ---- Phase C: cell update ----
  for (int r = wave; r < BR; r += 4){
    int n = base + r;
    if (n >= N) continue;
    float gi = gbuf[r][lane], gf = gbuf[r][64+lane], gg2 = gbuf[r][128+lane], go = gbuf[r][192+lane];
    float cn = sigmoidf_(gf)*c[(size_t)n*HH+lane] + sigmoidf_(gi)*tanhf(gg2);
    float hn = sigmoidf_(go)*tanhf(cn);
    c[(size_t)n*HH+lane] = cn;
    unsigned short hb = f2bf(hn);
    h_next[(size_t)n*HH+lane] = hb;
    if (h2_store) h2_store[(size_t)n*HH+lane] = hb;
  }
}

// ================= output head (bf16 inputs) =================
__global__ void out_gemm(const unsigned short* __restrict__ xr8, const unsigned short* __restrict__ h2s,
                         const float* __restrict__ Wout, const float* __restrict__ bout,
                         float* __restrict__ out, int N){
  int idx = blockIdx.x*blockDim.x + threadIdx.x;
  if (idx >= NF*N*OO) return;
  int o = idx & (OO-1);
  int row = idx >> 3;                     // tt*N + n
  const unsigned short* xv = xr8 + (size_t)row*HH;
  const unsigned short* hv = h2s + (size_t)row*HH;
  float acc = bout[o];
  #pragma unroll
  for (int k = 0; k < HH; ++k)
    acc += bf2f(xv[k])*Wout[k*OO+o] + bf2f(hv[k])*Wout[(HH+k)*OO+o];
  out[idx] = acc;
}

__global__ void copyk(const float* __restrict__ s, float* __restrict__ d, int n){
  int i = blockIdx.x*blockDim.x + threadIdx.x;
  if (i < n) d[i] = s[i];
}

extern "C" void kernel_launch(void* const* d_in, const int* in_sizes, int n_in,
                              void* d_out, int out_size, void* d_ws, size_t ws_size,
                              hipStream_t stream){
  const float* x      = (const float*)d_in[0];
  const int*   ei     = (const int*)  d_in[1];
  const float* ew     = (const float*)d_in[2];
  const float* sWr    = (const float*)d_in[3];
  const float* sWroot = (const float*)d_in[4];
  const float* sb     = (const float*)d_in[5];
  const float* l1Wr   = (const float*)d_in[6];
  const float* l1Wroot= (const float*)d_in[7];
  const float* l1b    = (const float*)d_in[8];
  const float* l2Wr   = (const float*)d_in[9];
  const float* l2Wroot= (const float*)d_in[10];
  const float* l2b    = (const float*)d_in[11];
  const float* Wout   = (const float*)d_in[12];
  const float* bout   = (const float*)d_in[13];

  const int E = in_sizes[2];
  const int N = in_sizes[0] / (TT*FF);
  const int* src = ei;
  const int* dst = ei + E;

  float* out0   = (float*)d_out;              // [4,N,8]
  float* c2out  = out0 + (size_t)NF*N*OO;     // [N,64]
  float* embout = c2out + (size_t)N*HH;       // [12,N,64]

  float* w = (float*)d_ws;
  float* agg_x  = w;  w += (size_t)TT*N*FF;   // fp32 sage agg
  float* cbuf   = w;  w += (size_t)N*HH;
  float* invd   = w;  w += N;
  int*   cnt    = (int*)w;  w += N;
  int*   fill   = (int*)w;  w += N;
  int*   ptr    = (int*)w;  w += (N+2);       // keep int2 array 8B-aligned
  int2*  csr_sw = (int2*)w; w += (size_t)2*E;
  unsigned short* Wf1 = (unsigned short*)w; w += (size_t)16*8*64*8/2;
  unsigned short* Wf2 = (unsigned short*)w; w += (size_t)16*8*64*8/2;
  unsigned short* xb     = (unsigned short*)w; w += (size_t)TT*N*FF/2;
  unsigned short* xrb    = (unsigned short*)w; w += (size_t)TT*N*HH/2;
  unsigned short* xraggb = (unsigned short*)w; w += (size_t)TT*N*HH/2;
  unsigned short* hA     = (unsigned short*)w; w += (size_t)N*HH/2;
  unsigned short* hB     = (unsigned short*)w; w += (size_t)N*HH/2;
  unsigned short* h2s    = (unsigned short*)w; w += (size_t)NF*N*HH/2;

  hipMemsetAsync(cnt,  0, (size_t)N*4, stream);
  hipMemsetAsync(fill, 0, (size_t)N*4, stream);
  hipMemsetAsync(hA,   0, (size_t)N*HH*2, stream);  // h0 (bf16 zero = 0)
  hipMemsetAsync(cbuf, 0, (size_t)N*HH*4, stream);  // c0

  hist_kernel<<<(E+255)/256, 256, 0, stream>>>(dst, cnt, E);
  scan_kernel<<<1, 1024, 0, stream>>>(cnt, ptr, invd, N);
  fill_kernel<<<(E+255)/256, 256, 0, stream>>>(src, dst, ew, ptr, fill, csr_sw, E);

  pack_wfrag<<<(16*8*64*8+255)/256, 256, 0, stream>>>(l1Wr, l1Wroot, Wf1);
  pack_wfrag<<<(16*8*64*8+255)/256, 256, 0, stream>>>(l2Wr, l2Wroot, Wf2);
  bf16_conv<<<((size_t)TT*N*FF+255)/256, 256, 0, stream>>>(x, xb, TT*N*FF);

  sage_gather<<<(N+3)/4, 256, 0, stream>>>(xb, ptr, csr_sw, invd, agg_x, N);
  sage_gemm<<<((size_t)TT*N*HH+255)/256, 256, 0, stream>>>(x, agg_x, sWr, sWroot, sb,
                                                           embout, xrb, N);
  xr_gather<<<(N+3)/4, 256, 0, stream>>>(xrb, ptr, csr_sw, invd, xraggb, N);

  const int sBlocks = (N+BR-1)/BR;      // 1250
  unsigned short* hp = hA; unsigned short* hn = hB;
  // LSTM1
  for (int t = 0; t < TT; ++t){
    lstm_mfma<<<sBlocks, 256, 0, stream>>>(xrb + (size_t)t*N*HH, xraggb + (size_t)t*N*HH,
                                           hp, hn, cbuf, invd, ptr, csr_sw,
                                           Wf1, l1b, nullptr, N);
    unsigned short* tmp = hp; hp = hn; hn = tmp;
  }
  // LSTM2 (continues from h1[-1], c1); h2 stored for t>=8
  for (int t = 0; t < TT; ++t){
    unsigned short* store = (t >= TT-NF) ? (h2s + (size_t)(t-(TT-NF))*N*HH) : nullptr;
    lstm_mfma<<<sBlocks, 256, 0, stream>>>(xrb + (size_t)t*N*HH, xraggb + (size_t)t*N*HH,
                                           hp, hn, cbuf, invd, ptr, csr_sw,
                                           Wf2, l2b, store, N);
    unsigned short* tmp = hp; hp = hn; hn = tmp;
  }

  out_gemm<<<((size_t)NF*N*OO+255)/256, 256, 0, stream>>>(xrb + (size_t)(TT-NF)*N*HH, h2s,
                                                          Wout, bout, out0, N);
  copyk<<<((size_t)N*HH+255)/256, 256, 0, stream>>>(cbuf, c2out, N*HH);
}

// Round 12
// 1142.847 us; speedup vs baseline: 4.2853x; 1.1080x over previous
//
#include <hip/hip_runtime.h>
#include <math.h>

#define TT 12
#define FF 32
#define HH 64
#define OO 8
#define GG 256   // 4*HH
#define NF 4     // NUM_FUTURE
#define BR 16    // nodes per lstm block

typedef __bf16 bf16x8 __attribute__((ext_vector_type(8)));
typedef float  f32x4  __attribute__((ext_vector_type(4)));

__device__ __forceinline__ float sigmoidf_(float x){ return 1.f/(1.f+expf(-x)); }
__device__ __forceinline__ unsigned short f2bf(float f){   // round-to-nearest-even
  unsigned int u = __float_as_uint(f);
  u += 0x7FFFu + ((u >> 16) & 1u);
  return (unsigned short)(u >> 16);
}
__device__ __forceinline__ float bf2f(unsigned short b){
  return __uint_as_float(((unsigned int)b) << 16);
}

// ================= CSR build =================
__global__ void hist_kernel(const int* __restrict__ dst, int* __restrict__ cnt, int E){
  int e = blockIdx.x*blockDim.x + threadIdx.x;
  if (e < E) atomicAdd(&cnt[dst[e]], 1);
}

__global__ __launch_bounds__(1024) void scan_kernel(const int* __restrict__ cnt,
                                                    int* __restrict__ ptr,
                                                    float* __restrict__ invd, int N){
  __shared__ int buf[1024];
  __shared__ int carry;
  if (threadIdx.x == 0) carry = 0;
  __syncthreads();
  for (int base = 0; base < N; base += 1024){
    int i = base + threadIdx.x;
    int v = (i < N) ? cnt[i] : 0;
    buf[threadIdx.x] = v;
    __syncthreads();
    for (int off = 1; off < 1024; off <<= 1){
      int t = (threadIdx.x >= off) ? buf[threadIdx.x - off] : 0;
      __syncthreads();
      buf[threadIdx.x] += t;
      __syncthreads();
    }
    int incl = buf[threadIdx.x];
    if (i < N){
      ptr[i] = carry + incl - v;
      invd[i] = 1.f / fmaxf((float)v, 1.f);
    }
    __syncthreads();
    if (threadIdx.x == 1023){
      carry += incl;
      if (base + 1024 >= N) ptr[N] = carry;
    }
    __syncthreads();
  }
}

__global__ void fill_kernel(const int* __restrict__ src, const int* __restrict__ dst,
                            const float* __restrict__ ew, const int* __restrict__ ptr,
                            int* __restrict__ fill, int2* __restrict__ csr_sw, int E){
  int e = blockIdx.x*blockDim.x + threadIdx.x;
  if (e >= E) return;
  int d = dst[e];
  int pos = ptr[d] + atomicAdd(&fill[d], 1);
  int2 m; m.x = src[e]; m.y = __float_as_int(ew[e]);
  csr_sw[pos] = m;
}

// ====== fp32 -> bf16 bulk convert ======
__global__ void bf16_conv(const float* __restrict__ in, unsigned short* __restrict__ out, int n){
  int i = blockIdx.x*blockDim.x + threadIdx.x;
  if (i < n) out[i] = f2bf(in[i]);
}

// ====== MFMA B-fragment weight packing (bf16), LSTM K=256 ======
__global__ void pack_wfrag(const float* __restrict__ Wr, const float* __restrict__ Wroot,
                           unsigned short* __restrict__ Wfrag){
  int idx = blockIdx.x*256 + threadIdx.x;
  if (idx >= 16*8*64*8) return;
  int e  = idx & 7;
  int l  = (idx >> 3) & 63;
  int ks = (idx >> 9) & 7;
  int jt = idx >> 12;
  int k = ks*32 + (l>>4)*8 + e;
  int j = jt*16 + (l&15);
  float v = (k < 128) ? Wr[(size_t)k*GG + j] : Wroot[(size_t)(k-128)*GG + j];
  Wfrag[idx] = f2bf(v);
}

// ====== MFMA B-fragment packing, SAGE K=64 (rows [Wr(32); Wroot(32)], 64 cols) ======
__global__ void pack_sfrag(const float* __restrict__ Wr, const float* __restrict__ Wroot,
                           unsigned short* __restrict__ Sfrag){
  int idx = blockIdx.x*256 + threadIdx.x;
  if (idx >= 4*2*64*8) return;
  int e  = idx & 7;
  int l  = (idx >> 3) & 63;
  int ks = (idx >> 9) & 1;
  int jt = idx >> 10;
  int k = ks*32 + (l>>4)*8 + e;   // 0..63
  int j = jt*16 + (l&15);
  float v = (k < 32) ? Wr[(size_t)k*HH + j] : Wroot[(size_t)(k-32)*HH + j];
  Sfrag[idx] = f2bf(v);
}

// ========== SAGE aggregation (bf16 in/out): t-inner, edge-unroll 2 ==========
__global__ __launch_bounds__(256) void sage_gather(
    const unsigned short* __restrict__ xb, const int* __restrict__ ptr,
    const int2* __restrict__ csr_sw,
    const float* __restrict__ invd, unsigned short* __restrict__ aggb, int N){
  int wave = threadIdx.x >> 6, lane = threadIdx.x & 63;
  int f = lane & 31, tp = lane >> 5;
  int n = blockIdx.x*4 + wave;
  if (n >= N) return;
  int beg = ptr[n], end = ptr[n+1];
  float id = invd[n];
  float acc[TT/2];
  #pragma unroll
  for (int th = 0; th < TT/2; ++th) acc[th] = 0.f;
  const size_t plane = (size_t)N*FF;
  int e = beg;
  for (; e+2 <= end; e += 2){
    int2 m0 = csr_sw[e], m1 = csr_sw[e+1];
    const unsigned short* p0 = xb + (size_t)m0.x*FF + f + (size_t)tp*plane;
    const unsigned short* p1 = xb + (size_t)m1.x*FF + f + (size_t)tp*plane;
    float w0 = __int_as_float(m0.y), w1 = __int_as_float(m1.y);
    #pragma unroll
    for (int th = 0; th < TT/2; ++th)
      acc[th] += bf2f(p0[2*th*plane])*w0 + bf2f(p1[2*th*plane])*w1;
  }
  for (; e < end; ++e){
    int2 m = csr_sw[e];
    const unsigned short* p = xb + (size_t)m.x*FF + f + (size_t)tp*plane;
    float wv = __int_as_float(m.y);
    #pragma unroll
    for (int th = 0; th < TT/2; ++th)
      acc[th] += bf2f(p[2*th*plane])*wv;
  }
  #pragma unroll
  for (int th = 0; th < TT/2; ++th)
    aggb[(size_t)(2*th+tp)*plane + (size_t)n*FF + f] = f2bf(acc[th] * id);  // pre-normalized
}

// ====== SAGE linear via MFMA: emb(fp32) = [aggb|xb] @ Sfrag + b ; xrb = bf16 relu ======
// block = 4 waves x 16 rows = 64 rows; A-frags straight from global (16B/lane).
__global__ __launch_bounds__(256) void sage_mfma(
    const unsigned short* __restrict__ aggb, const unsigned short* __restrict__ xb,
    const unsigned short* __restrict__ Sfrag, const float* __restrict__ bias,
    float* __restrict__ emb, unsigned short* __restrict__ xrb, int Mrows){
  int tid = threadIdx.x, wave = tid >> 6, lane = tid & 63;
  int rbase = blockIdx.x*64 + wave*16;
  if (rbase >= Mrows) return;
  int l15 = lane & 15, l4 = lane >> 4;
  int row = rbase + l15;
  bf16x8 af0 = *(const bf16x8*)&aggb[(size_t)row*FF + l4*8];   // k 0..31
  bf16x8 af1 = *(const bf16x8*)&xb  [(size_t)row*FF + l4*8];   // k 32..63
  f32x4 acc[4];
  #pragma unroll
  for (int jt = 0; jt < 4; ++jt){
    float bv = bias[jt*16 + l15];
    acc[jt][0]=bv; acc[jt][1]=bv; acc[jt][2]=bv; acc[jt][3]=bv;
  }
  #pragma unroll
  for (int jt = 0; jt < 4; ++jt){
    bf16x8 b0 = *(const bf16x8*)&Sfrag[(size_t)(((jt*2+0)*64) + lane) * 8];
    bf16x8 b1 = *(const bf16x8*)&Sfrag[(size_t)(((jt*2+1)*64) + lane) * 8];
    acc[jt] = __builtin_amdgcn_mfma_f32_16x16x32_bf16(af0, b0, acc[jt], 0, 0, 0);
    acc[jt] = __builtin_amdgcn_mfma_f32_16x16x32_bf16(af1, b1, acc[jt], 0, 0, 0);
  }
  // D layout: col = lane&15, row = (lane>>4)*4 + i (m89-verified)
  #pragma unroll
  for (int jt = 0; jt < 4; ++jt){
    int col = jt*16 + l15;
    #pragma unroll
    for (int i = 0; i < 4; ++i){
      int ro = rbase + l4*4 + i;
      float v = acc[jt][i];
      emb[(size_t)ro*HH + col] = v;
      xrb[(size_t)ro*HH + col] = f2bf(fmaxf(v, 0.f));
    }
  }
}

// ========== xr aggregation (bf16 in/out): t-inner (12 acc), edge-unroll 2 ==========
__global__ __launch_bounds__(256) void xr_gather(
    const unsigned short* __restrict__ xrb, const int* __restrict__ ptr,
    const int2* __restrict__ csr_sw,
    const float* __restrict__ invd, unsigned short* __restrict__ xr_aggb, int N){
  int wave = threadIdx.x >> 6, lane = threadIdx.x & 63;
  int n = blockIdx.x*4 + wave;
  if (n >= N) return;
  int beg = ptr[n], end = ptr[n+1];
  float id = invd[n];
  float acc[TT];
  #pragma unroll
  for (int t = 0; t < TT; ++t) acc[t] = 0.f;
  const size_t plane = (size_t)N*HH;
  int e = beg;
  for (; e+2 <= end; e += 2){
    int2 m0 = csr_sw[e], m1 = csr_sw[e+1];
    const unsigned short* p0 = xrb + (size_t)m0.x*HH + lane;
    const unsigned short* p1 = xrb + (size_t)m1.x*HH + lane;
    float w0 = __int_as_float(m0.y), w1 = __int_as_float(m1.y);
    #pragma unroll
    for (int t = 0; t < TT; ++t)
      acc[t] += bf2f(p0[t*plane])*w0 + bf2f(p1[t*plane])*w1;
  }
  for (; e < end; ++e){
    int2 m = csr_sw[e];
    const unsigned short* p = xrb + (size_t)m.x*HH + lane;
    float wv = __int_as_float(m.y);
    #pragma unroll
    for (int t = 0; t < TT; ++t)
      acc[t] += bf2f(p[t*plane])*wv;
  }
  #pragma unroll
  for (int t = 0; t < TT; ++t)
    xr_aggb[(size_t)t*plane + (size_t)n*HH + lane] = f2bf(acc[t] * id);  // pre-normalized
}

// ============ fused step: bf16 h-gather + bf16 MFMA gates GEMM + cell ============
__global__ __launch_bounds__(256) void lstm_mfma(
    const unsigned short* __restrict__ xrb_t, const unsigned short* __restrict__ xraggb_t,
    const unsigned short* __restrict__ h_prev, unsigned short* __restrict__ h_next,
    float* __restrict__ c, const float* __restrict__ invd,
    const int* __restrict__ ptr, const int2* __restrict__ csr_sw,
    const unsigned short* __restrict__ Wfrag, const float* __restrict__ bias,
    unsigned short* __restrict__ h2_store, int N){
  __shared__ __align__(16) unsigned short Albuf[BR][264];  // bf16 A-tile, padded
  __shared__ float gbuf[BR][260];                          // fp32 gates
  int tid = threadIdx.x, wave = tid >> 6, lane = tid & 63;
  int base = blockIdx.x * BR;

  // ---- Phase A: gather h_agg (unroll-8) + stage bf16 A-tile ----
  for (int r4 = 0; r4 < 4; ++r4){
    int r = wave*4 + r4;
    int n = base + r;
    if (n < N){
      float id = invd[n];
      int beg = ptr[n], end = ptr[n+1];
      float a0=0.f,a1=0.f,a2=0.f,a3=0.f,a4=0.f,a5=0.f,a6=0.f,a7=0.f;
      int e = beg;
      for (; e+8 <= end; e += 8){
        int2 m0=csr_sw[e+0], m1=csr_sw[e+1], m2=csr_sw[e+2], m3=csr_sw[e+3];
        int2 m4=csr_sw[e+4], m5=csr_sw[e+5], m6=csr_sw[e+6], m7=csr_sw[e+7];
        a0 += bf2f(h_prev[(size_t)m0.x*HH+lane])*__int_as_float(m0.y);
        a1 += bf2f(h_prev[(size_t)m1.x*HH+lane])*__int_as_float(m1.y);
        a2 += bf2f(h_prev[(size_t)m2.x*HH+lane])*__int_as_float(m2.y);
        a3 += bf2f(h_prev[(size_t)m3.x*HH+lane])*__int_as_float(m3.y);
        a4 += bf2f(h_prev[(size_t)m4.x*HH+lane])*__int_as_float(m4.y);
        a5 += bf2f(h_prev[(size_t)m5.x*HH+lane])*__int_as_float(m5.y);
        a6 += bf2f(h_prev[(size_t)m6.x*HH+lane])*__int_as_float(m6.y);
        a7 += bf2f(h_prev[(size_t)m7.x*HH+lane])*__int_as_float(m7.y);
      }
      for (; e < end; ++e){
        int2 m = csr_sw[e];
        a0 += bf2f(h_prev[(size_t)m.x*HH+lane])*__int_as_float(m.y);
      }
      float hag = (((a0+a1)+(a2+a3))+((a4+a5)+(a6+a7))) * id;
      Albuf[r][    lane] = xraggb_t[(size_t)n*HH + lane];
      Albuf[r][ 64+lane] = f2bf(hag);
      Albuf[r][128+lane] = xrb_t [(size_t)n*HH + lane];
      Albuf[r][192+lane] = h_prev[(size_t)n*HH + lane];
    } else {
      Albuf[r][lane] = Albuf[r][64+lane] = Albuf[r][128+lane] = Albuf[r][192+lane] = 0;
    }
  }
  __syncthreads();

  // ---- Phase B: MFMA; wave owns cols [64w,64w+64) = 4 tiles of 16 ----
  int l15 = lane & 15, l4 = lane >> 4;
  f32x4 acc[4];
  #pragma unroll
  for (int jtl = 0; jtl < 4; ++jtl){
    float bv = bias[wave*64 + jtl*16 + l15];
    acc[jtl][0]=bv; acc[jtl][1]=bv; acc[jtl][2]=bv; acc[jtl][3]=bv;
  }
  #pragma unroll
  for (int ks = 0; ks < 8; ++ks){
    bf16x8 af = *(const bf16x8*)&Albuf[l15][ks*32 + l4*8];
    #pragma unroll
    for (int jtl = 0; jtl < 4; ++jtl){
      int jt = wave*4 + jtl;
      bf16x8 bf = *(const bf16x8*)&Wfrag[(size_t)(((jt*8 + ks)*64) + lane) * 8];
      acc[jtl] = __builtin_amdgcn_mfma_f32_16x16x32_bf16(af, bf, acc[jtl], 0, 0, 0);
    }
  }
  // gates -> LDS: D layout col=lane&15, row=(lane>>4)*4+i  (m89-verified)
  #pragma unroll
  for (int jtl = 0; jtl < 4; ++jtl){
    int col = wave*64 + jtl*16 + l15;
    #pragma unroll
    for (int i = 0; i < 4; ++i)
      gbuf[l4*4 + i][col] = acc[jtl][i];
  }
  __syncthreads();

  // ---- Phase C: cell update ----
  for (int r = wave; r < BR; r += 4){
    int n = base + r;
    if (n >= N) continue;
    float gi = gbuf[r][lane], gf = gbuf[r][64+lane], gg2 = gbuf[r][128+lane], go = gbuf[r][192+lane];
    float cn = sigmoidf_(gf)*c[(size_t)n*HH+lane] + sigmoidf_(gi)*tanhf(gg2);
    float hn = sigmoidf_(go)*tanhf(cn);
    c[(size_t)n*HH+lane] = cn;
    unsigned short hb = f2bf(hn);
    h_next[(size_t)n*HH+lane] = hb;
    if (h2_store) h2_store[(size_t)n*HH+lane] = hb;
  }
}

// ================= output head (bf16 inputs) =================
__global__ void out_gemm(const unsigned short* __restrict__ xr8, const unsigned short* __restrict__ h2s,
                         const float* __restrict__ Wout, const float* __restrict__ bout,
                         float* __restrict__ out, int N){
  int idx = blockIdx.x*blockDim.x + threadIdx.x;
  if (idx >= NF*N*OO) return;
  int o = idx & (OO-1);
  int row = idx >> 3;                     // tt*N + n
  const unsigned short* xv = xr8 + (size_t)row*HH;
  const unsigned short* hv = h2s + (size_t)row*HH;
  float acc = bout[o];
  #pragma unroll
  for (int k = 0; k < HH; ++k)
    acc += bf2f(xv[k])*Wout[k*OO+o] + bf2f(hv[k])*Wout[(HH+k)*OO+o];
  out[idx] = acc;
}

__global__ void copyk(const float* __restrict__ s, float* __restrict__ d, int n){
  int i = blockIdx.x*blockDim.x + threadIdx.x;
  if (i < n) d[i] = s[i];
}

extern "C" void kernel_launch(void* const* d_in, const int* in_sizes, int n_in,
                              void* d_out, int out_size, void* d_ws, size_t ws_size,
                              hipStream_t stream){
  const float* x      = (const float*)d_in[0];
  const int*   ei     = (const int*)  d_in[1];
  const float* ew     = (const float*)d_in[2];
  const float* sWr    = (const float*)d_in[3];
  const float* sWroot = (const float*)d_in[4];
  const float* sb     = (const float*)d_in[5];
  const float* l1Wr   = (const float*)d_in[6];
  const float* l1Wroot= (const float*)d_in[7];
  const float* l1b    = (const float*)d_in[8];
  const float* l2Wr   = (const float*)d_in[9];
  const float* l2Wroot= (const float*)d_in[10];
  const float* l2b    = (const float*)d_in[11];
  const float* Wout   = (const float*)d_in[12];
  const float* bout   = (const float*)d_in[13];

  const int E = in_sizes[2];
  const int N = in_sizes[0] / (TT*FF);
  const int* src = ei;
  const int* dst = ei + E;

  float* out0   = (float*)d_out;              // [4,N,8]
  float* c2out  = out0 + (size_t)NF*N*OO;     // [N,64]
  float* embout = c2out + (size_t)N*HH;       // [12,N,64]

  float* w = (float*)d_ws;
  float* cbuf   = w;  w += (size_t)N*HH;
  float* invd   = w;  w += N;
  int*   cnt    = (int*)w;  w += N;
  int*   fill   = (int*)w;  w += N;
  int*   ptr    = (int*)w;  w += (N+2);       // keep int2 array 8B-aligned
  int2*  csr_sw = (int2*)w; w += (size_t)2*E;
  unsigned short* Wf1 = (unsigned short*)w; w += (size_t)16*8*64*8/2;
  unsigned short* Wf2 = (unsigned short*)w; w += (size_t)16*8*64*8/2;
  unsigned short* Sfg = (unsigned short*)w; w += (size_t)4*2*64*8/2;
  unsigned short* xb     = (unsigned short*)w; w += (size_t)TT*N*FF/2;
  unsigned short* aggb   = (unsigned short*)w; w += (size_t)TT*N*FF/2;
  unsigned short* xrb    = (unsigned short*)w; w += (size_t)TT*N*HH/2;
  unsigned short* xraggb = (unsigned short*)w; w += (size_t)TT*N*HH/2;
  unsigned short* hA     = (unsigned short*)w; w += (size_t)N*HH/2;
  unsigned short* hB     = (unsigned short*)w; w += (size_t)N*HH/2;
  unsigned short* h2s    = (unsigned short*)w; w += (size_t)NF*N*HH/2;

  hipMemsetAsync(cnt,  0, (size_t)N*4, stream);
  hipMemsetAsync(fill, 0, (size_t)N*4, stream);
  hipMemsetAsync(hA,   0, (size_t)N*HH*2, stream);  // h0 (bf16 zero = 0)
  hipMemsetAsync(cbuf, 0, (size_t)N*HH*4, stream);  // c0

  hist_kernel<<<(E+255)/256, 256, 0, stream>>>(dst, cnt, E);
  scan_kernel<<<1, 1024, 0, stream>>>(cnt, ptr, invd, N);
  fill_kernel<<<(E+255)/256, 256, 0, stream>>>(src, dst, ew, ptr, fill, csr_sw, E);

  pack_wfrag<<<(16*8*64*8+255)/256, 256, 0, stream>>>(l1Wr, l1Wroot, Wf1);
  pack_wfrag<<<(16*8*64*8+255)/256, 256, 0, stream>>>(l2Wr, l2Wroot, Wf2);
  pack_sfrag<<<(4*2*64*8+255)/256, 256, 0, stream>>>(sWr, sWroot, Sfg);
  bf16_conv<<<((size_t)TT*N*FF+255)/256, 256, 0, stream>>>(x, xb, TT*N*FF);

  sage_gather<<<(N+3)/4, 256, 0, stream>>>(xb, ptr, csr_sw, invd, aggb, N);
  {
    int Mrows = TT*N;
    sage_mfma<<<(Mrows+63)/64, 256, 0, stream>>>(aggb, xb, Sfg, sb, embout, xrb, Mrows);
  }
  xr_gather<<<(N+3)/4, 256, 0, stream>>>(xrb, ptr, csr_sw, invd, xraggb, N);

  const int sBlocks = (N+BR-1)/BR;      // 1250
  unsigned short* hp = hA; unsigned short* hn = hB;
  // LSTM1
  for (int t = 0; t < TT; ++t){
    lstm_mfma<<<sBlocks, 256, 0, stream>>>(xrb + (size_t)t*N*HH, xraggb + (size_t)t*N*HH,
                                           hp, hn, cbuf, invd, ptr, csr_sw,
                                           Wf1, l1b, nullptr, N);
    unsigned short* tmp = hp; hp = hn; hn = tmp;
  }
  // LSTM2 (continues from h1[-1], c1); h2 stored for t>=8
  for (int t = 0; t < TT; ++t){
    unsigned short* store = (t >= TT-NF) ? (h2s + (size_t)(t-(TT-NF))*N*HH) : nullptr;
    lstm_mfma<<<sBlocks, 256, 0, stream>>>(xrb + (size_t)t*N*HH, xraggb + (size_t)t*N*HH,
                                           hp, hn, cbuf, invd, ptr, csr_sw,
                                           Wf2, l2b, store, N);
    unsigned short* tmp = hp; hp = hn; hn = tmp;
  }

  out_gemm<<<((size_t)NF*N*OO+255)/256, 256, 0, stream>>>(xrb + (size_t)(TT-NF)*N*HH, h2s,
                                                          Wout, bout, out0, N);
  copyk<<<((size_t)N*HH+255)/256, 256, 0, stream>>>(cbuf, c2out, N*HH);
}

// Round 13
// 1114.629 us; speedup vs baseline: 4.3938x; 1.0253x over previous
//
#include <hip/hip_runtime.h>
#include <math.h>

#define TT 12
#define FF 32
#define HH 64
#define OO 8
#define GG 256   // 4*HH
#define NF 4     // NUM_FUTURE
#define BR 16    // nodes per lstm block

typedef __bf16 bf16x8 __attribute__((ext_vector_type(8)));
typedef float  f32x4  __attribute__((ext_vector_type(4)));

__device__ __forceinline__ float sigmoidf_(float x){ return 1.f/(1.f+expf(-x)); }
__device__ __forceinline__ unsigned short f2bf(float f){   // round-to-nearest-even
  unsigned int u = __float_as_uint(f);
  u += 0x7FFFu + ((u >> 16) & 1u);
  return (unsigned short)(u >> 16);
}
__device__ __forceinline__ float bf2f(unsigned short b){
  return __uint_as_float(((unsigned int)b) << 16);
}

// ================= CSR build =================
__global__ void hist_kernel(const int* __restrict__ dst, int* __restrict__ cnt, int E){
  int e = blockIdx.x*blockDim.x + threadIdx.x;
  if (e < E) atomicAdd(&cnt[dst[e]], 1);
}

__global__ __launch_bounds__(1024) void scan_kernel(const int* __restrict__ cnt,
                                                    int* __restrict__ ptr,
                                                    float* __restrict__ invd, int N){
  __shared__ int buf[1024];
  __shared__ int carry;
  if (threadIdx.x == 0) carry = 0;
  __syncthreads();
  for (int base = 0; base < N; base += 1024){
    int i = base + threadIdx.x;
    int v = (i < N) ? cnt[i] : 0;
    buf[threadIdx.x] = v;
    __syncthreads();
    for (int off = 1; off < 1024; off <<= 1){
      int t = (threadIdx.x >= off) ? buf[threadIdx.x - off] : 0;
      __syncthreads();
      buf[threadIdx.x] += t;
      __syncthreads();
    }
    int incl = buf[threadIdx.x];
    if (i < N){
      ptr[i] = carry + incl - v;
      invd[i] = 1.f / fmaxf((float)v, 1.f);
    }
    __syncthreads();
    if (threadIdx.x == 1023){
      carry += incl;
      if (base + 1024 >= N) ptr[N] = carry;
    }
    __syncthreads();
  }
}

__global__ void fill_kernel(const int* __restrict__ src, const int* __restrict__ dst,
                            const float* __restrict__ ew, const int* __restrict__ ptr,
                            int* __restrict__ fill, int2* __restrict__ csr_sw, int E){
  int e = blockIdx.x*blockDim.x + threadIdx.x;
  if (e >= E) return;
  int d = dst[e];
  int pos = ptr[d] + atomicAdd(&fill[d], 1);
  int2 m; m.x = src[e]; m.y = __float_as_int(ew[e]);
  csr_sw[pos] = m;
}

// ====== fp32 -> bf16 bulk convert ======
__global__ void bf16_conv(const float* __restrict__ in, unsigned short* __restrict__ out, int n){
  int i = blockIdx.x*blockDim.x + threadIdx.x;
  if (i < n) out[i] = f2bf(in[i]);
}

// ====== MFMA B-fragment weight packing (bf16), LSTM K=256 ======
__global__ void pack_wfrag(const float* __restrict__ Wr, const float* __restrict__ Wroot,
                           unsigned short* __restrict__ Wfrag){
  int idx = blockIdx.x*256 + threadIdx.x;
  if (idx >= 16*8*64*8) return;
  int e  = idx & 7;
  int l  = (idx >> 3) & 63;
  int ks = (idx >> 9) & 7;
  int jt = idx >> 12;
  int k = ks*32 + (l>>4)*8 + e;
  int j = jt*16 + (l&15);
  float v = (k < 128) ? Wr[(size_t)k*GG + j] : Wroot[(size_t)(k-128)*GG + j];
  Wfrag[idx] = f2bf(v);
}

// ====== MFMA B-fragment packing, SAGE K=64 ======
__global__ void pack_sfrag(const float* __restrict__ Wr, const float* __restrict__ Wroot,
                           unsigned short* __restrict__ Sfrag){
  int idx = blockIdx.x*256 + threadIdx.x;
  if (idx >= 4*2*64*8) return;
  int e  = idx & 7;
  int l  = (idx >> 3) & 63;
  int ks = (idx >> 9) & 1;
  int jt = idx >> 10;
  int k = ks*32 + (l>>4)*8 + e;   // 0..63
  int j = jt*16 + (l&15);
  float v = (k < 32) ? Wr[(size_t)k*HH + j] : Wroot[(size_t)(k-32)*HH + j];
  Sfrag[idx] = f2bf(v);
}

// ========== SAGE aggregation (bf16 in/out): t-inner, edge-unroll 4 ==========
__global__ __launch_bounds__(256) void sage_gather(
    const unsigned short* __restrict__ xb, const int* __restrict__ ptr,
    const int2* __restrict__ csr_sw,
    const float* __restrict__ invd, unsigned short* __restrict__ aggb, int N){
  int wave = threadIdx.x >> 6, lane = threadIdx.x & 63;
  int f = lane & 31, tp = lane >> 5;
  int n = blockIdx.x*4 + wave;
  if (n >= N) return;
  int beg = ptr[n], end = ptr[n+1];
  float id = invd[n];
  float acc[TT/2];
  #pragma unroll
  for (int th = 0; th < TT/2; ++th) acc[th] = 0.f;
  const size_t plane = (size_t)N*FF;
  int e = beg;
  for (; e+4 <= end; e += 4){
    int2 m0 = csr_sw[e], m1 = csr_sw[e+1], m2 = csr_sw[e+2], m3 = csr_sw[e+3];
    const unsigned short* p0 = xb + (size_t)m0.x*FF + f + (size_t)tp*plane;
    const unsigned short* p1 = xb + (size_t)m1.x*FF + f + (size_t)tp*plane;
    const unsigned short* p2 = xb + (size_t)m2.x*FF + f + (size_t)tp*plane;
    const unsigned short* p3 = xb + (size_t)m3.x*FF + f + (size_t)tp*plane;
    float w0 = __int_as_float(m0.y), w1 = __int_as_float(m1.y);
    float w2 = __int_as_float(m2.y), w3 = __int_as_float(m3.y);
    #pragma unroll
    for (int th = 0; th < TT/2; ++th)
      acc[th] += bf2f(p0[2*th*plane])*w0 + bf2f(p1[2*th*plane])*w1
               + bf2f(p2[2*th*plane])*w2 + bf2f(p3[2*th*plane])*w3;
  }
  for (; e < end; ++e){
    int2 m = csr_sw[e];
    const unsigned short* p = xb + (size_t)m.x*FF + f + (size_t)tp*plane;
    float wv = __int_as_float(m.y);
    #pragma unroll
    for (int th = 0; th < TT/2; ++th)
      acc[th] += bf2f(p[2*th*plane])*wv;
  }
  #pragma unroll
  for (int th = 0; th < TT/2; ++th)
    aggb[(size_t)(2*th+tp)*plane + (size_t)n*FF + f] = f2bf(acc[th] * id);  // pre-normalized
}

// ====== SAGE linear via MFMA: emb(fp32) = [aggb|xb] @ Sfrag + b ; xrb = bf16 relu ======
__global__ __launch_bounds__(256) void sage_mfma(
    const unsigned short* __restrict__ aggb, const unsigned short* __restrict__ xb,
    const unsigned short* __restrict__ Sfrag, const float* __restrict__ bias,
    float* __restrict__ emb, unsigned short* __restrict__ xrb, int Mrows){
  int tid = threadIdx.x, wave = tid >> 6, lane = tid & 63;
  int rbase = blockIdx.x*64 + wave*16;
  if (rbase >= Mrows) return;
  int l15 = lane & 15, l4 = lane >> 4;
  int row = rbase + l15;
  bf16x8 af0 = *(const bf16x8*)&aggb[(size_t)row*FF + l4*8];   // k 0..31
  bf16x8 af1 = *(const bf16x8*)&xb  [(size_t)row*FF + l4*8];   // k 32..63
  f32x4 acc[4];
  #pragma unroll
  for (int jt = 0; jt < 4; ++jt){
    float bv = bias[jt*16 + l15];
    acc[jt][0]=bv; acc[jt][1]=bv; acc[jt][2]=bv; acc[jt][3]=bv;
  }
  #pragma unroll
  for (int jt = 0; jt < 4; ++jt){
    bf16x8 b0 = *(const bf16x8*)&Sfrag[(size_t)(((jt*2+0)*64) + lane) * 8];
    bf16x8 b1 = *(const bf16x8*)&Sfrag[(size_t)(((jt*2+1)*64) + lane) * 8];
    acc[jt] = __builtin_amdgcn_mfma_f32_16x16x32_bf16(af0, b0, acc[jt], 0, 0, 0);
    acc[jt] = __builtin_amdgcn_mfma_f32_16x16x32_bf16(af1, b1, acc[jt], 0, 0, 0);
  }
  #pragma unroll
  for (int jt = 0; jt < 4; ++jt){
    int col = jt*16 + l15;
    #pragma unroll
    for (int i = 0; i < 4; ++i){
      int ro = rbase + l4*4 + i;
      float v = acc[jt][i];
      emb[(size_t)ro*HH + col] = v;
      xrb[(size_t)ro*HH + col] = f2bf(fmaxf(v, 0.f));
    }
  }
}

// ========== xr aggregation (bf16 in/out): t-inner (12 acc), edge-unroll 4 ==========
__global__ __launch_bounds__(256) void xr_gather(
    const unsigned short* __restrict__ xrb, const int* __restrict__ ptr,
    const int2* __restrict__ csr_sw,
    const float* __restrict__ invd, unsigned short* __restrict__ xr_aggb, int N){
  int wave = threadIdx.x >> 6, lane = threadIdx.x & 63;
  int n = blockIdx.x*4 + wave;
  if (n >= N) return;
  int beg = ptr[n], end = ptr[n+1];
  float id = invd[n];
  float acc[TT];
  #pragma unroll
  for (int t = 0; t < TT; ++t) acc[t] = 0.f;
  const size_t plane = (size_t)N*HH;
  int e = beg;
  for (; e+4 <= end; e += 4){
    int2 m0 = csr_sw[e], m1 = csr_sw[e+1], m2 = csr_sw[e+2], m3 = csr_sw[e+3];
    const unsigned short* p0 = xrb + (size_t)m0.x*HH + lane;
    const unsigned short* p1 = xrb + (size_t)m1.x*HH + lane;
    const unsigned short* p2 = xrb + (size_t)m2.x*HH + lane;
    const unsigned short* p3 = xrb + (size_t)m3.x*HH + lane;
    float w0 = __int_as_float(m0.y), w1 = __int_as_float(m1.y);
    float w2 = __int_as_float(m2.y), w3 = __int_as_float(m3.y);
    #pragma unroll
    for (int t = 0; t < TT; ++t)
      acc[t] += bf2f(p0[t*plane])*w0 + bf2f(p1[t*plane])*w1
              + bf2f(p2[t*plane])*w2 + bf2f(p3[t*plane])*w3;
  }
  for (; e < end; ++e){
    int2 m = csr_sw[e];
    const unsigned short* p = xrb + (size_t)m.x*HH + lane;
    float wv = __int_as_float(m.y);
    #pragma unroll
    for (int t = 0; t < TT; ++t)
      acc[t] += bf2f(p[t*plane])*wv;
  }
  #pragma unroll
  for (int t = 0; t < TT; ++t)
    xr_aggb[(size_t)t*plane + (size_t)n*HH + lane] = f2bf(acc[t] * id);  // pre-normalized
}

// ====== fused step, 16 waves: per-wave h-gather + MFMA col-tile + cell ======
// wave w: Phase A row w; Phase B col-tile w (16 cols, 8 MFMAs); Phase C row w.
__global__ __launch_bounds__(1024) void lstm_mfma(
    const unsigned short* __restrict__ xrb_t, const unsigned short* __restrict__ xraggb_t,
    const unsigned short* __restrict__ h_prev, unsigned short* __restrict__ h_next,
    float* __restrict__ c, const float* __restrict__ invd,
    const int* __restrict__ ptr, const int2* __restrict__ csr_sw,
    const unsigned short* __restrict__ Wfrag, const float* __restrict__ bias,
    unsigned short* __restrict__ h2_store, int N){
  __shared__ __align__(16) unsigned short Albuf[BR][264];  // bf16 A-tile, padded
  __shared__ float gbuf[BR][260];                          // fp32 gates
  int tid = threadIdx.x, wave = tid >> 6, lane = tid & 63;
  int base = blockIdx.x * BR;
  int n = base + wave;                  // this wave's node

  // ---- Phase A: one row per wave, gather h_agg (unroll-8) + stage bf16 A-tile ----
  if (n < N){
    float id = invd[n];
    int beg = ptr[n], end = ptr[n+1];
    float a0=0.f,a1=0.f,a2=0.f,a3=0.f,a4=0.f,a5=0.f,a6=0.f,a7=0.f;
    int e = beg;
    for (; e+8 <= end; e += 8){
      int2 m0=csr_sw[e+0], m1=csr_sw[e+1], m2=csr_sw[e+2], m3=csr_sw[e+3];
      int2 m4=csr_sw[e+4], m5=csr_sw[e+5], m6=csr_sw[e+6], m7=csr_sw[e+7];
      a0 += bf2f(h_prev[(size_t)m0.x*HH+lane])*__int_as_float(m0.y);
      a1 += bf2f(h_prev[(size_t)m1.x*HH+lane])*__int_as_float(m1.y);
      a2 += bf2f(h_prev[(size_t)m2.x*HH+lane])*__int_as_float(m2.y);
      a3 += bf2f(h_prev[(size_t)m3.x*HH+lane])*__int_as_float(m3.y);
      a4 += bf2f(h_prev[(size_t)m4.x*HH+lane])*__int_as_float(m4.y);
      a5 += bf2f(h_prev[(size_t)m5.x*HH+lane])*__int_as_float(m5.y);
      a6 += bf2f(h_prev[(size_t)m6.x*HH+lane])*__int_as_float(m6.y);
      a7 += bf2f(h_prev[(size_t)m7.x*HH+lane])*__int_as_float(m7.y);
    }
    for (; e < end; ++e){
      int2 m = csr_sw[e];
      a0 += bf2f(h_prev[(size_t)m.x*HH+lane])*__int_as_float(m.y);
    }
    float hag = (((a0+a1)+(a2+a3))+((a4+a5)+(a6+a7))) * id;
    Albuf[wave][    lane] = xraggb_t[(size_t)n*HH + lane];
    Albuf[wave][ 64+lane] = f2bf(hag);
    Albuf[wave][128+lane] = xrb_t [(size_t)n*HH + lane];
    Albuf[wave][192+lane] = h_prev[(size_t)n*HH + lane];
  } else {
    Albuf[wave][lane] = Albuf[wave][64+lane] = Albuf[wave][128+lane] = Albuf[wave][192+lane] = 0;
  }
  __syncthreads();

  // ---- Phase B: wave owns col-tile jt = wave (cols 16w..16w+16), 8 MFMAs ----
  int l15 = lane & 15, l4 = lane >> 4;
  int jt = wave;
  f32x4 acc;
  {
    float bv = bias[jt*16 + l15];
    acc[0]=bv; acc[1]=bv; acc[2]=bv; acc[3]=bv;
  }
  #pragma unroll
  for (int ks = 0; ks < 8; ++ks){
    bf16x8 af = *(const bf16x8*)&Albuf[l15][ks*32 + l4*8];
    bf16x8 bf = *(const bf16x8*)&Wfrag[(size_t)(((jt*8 + ks)*64) + lane) * 8];
    acc = __builtin_amdgcn_mfma_f32_16x16x32_bf16(af, bf, acc, 0, 0, 0);
  }
  // D layout: col = lane&15, row = (lane>>4)*4 + i (m89-verified)
  {
    int col = jt*16 + l15;
    #pragma unroll
    for (int i = 0; i < 4; ++i)
      gbuf[l4*4 + i][col] = acc[i];
  }
  __syncthreads();

  // ---- Phase C: one row per wave ----
  if (n < N){
    int r = wave;
    float gi = gbuf[r][lane], gf = gbuf[r][64+lane], gg2 = gbuf[r][128+lane], go = gbuf[r][192+lane];
    float cn = sigmoidf_(gf)*c[(size_t)n*HH+lane] + sigmoidf_(gi)*tanhf(gg2);
    float hn = sigmoidf_(go)*tanhf(cn);
    c[(size_t)n*HH+lane] = cn;
    unsigned short hb = f2bf(hn);
    h_next[(size_t)n*HH+lane] = hb;
    if (h2_store) h2_store[(size_t)n*HH+lane] = hb;
  }
}

// ================= output head (bf16 inputs) =================
__global__ void out_gemm(const unsigned short* __restrict__ xr8, const unsigned short* __restrict__ h2s,
                         const float* __restrict__ Wout, const float* __restrict__ bout,
                         float* __restrict__ out, int N){
  int idx = blockIdx.x*blockDim.x + threadIdx.x;
  if (idx >= NF*N*OO) return;
  int o = idx & (OO-1);
  int row = idx >> 3;                     // tt*N + n
  const unsigned short* xv = xr8 + (size_t)row*HH;
  const unsigned short* hv = h2s + (size_t)row*HH;
  float acc = bout[o];
  #pragma unroll
  for (int k = 0; k < HH; ++k)
    acc += bf2f(xv[k])*Wout[k*OO+o] + bf2f(hv[k])*Wout[(HH+k)*OO+o];
  out[idx] = acc;
}

__global__ void copyk(const float* __restrict__ s, float* __restrict__ d, int n){
  int i = blockIdx.x*blockDim.x + threadIdx.x;
  if (i < n) d[i] = s[i];
}

extern "C" void kernel_launch(void* const* d_in, const int* in_sizes, int n_in,
                              void* d_out, int out_size, void* d_ws, size_t ws_size,
                              hipStream_t stream){
  const float* x      = (const float*)d_in[0];
  const int*   ei     = (const int*)  d_in[1];
  const float* ew     = (const float*)d_in[2];
  const float* sWr    = (const float*)d_in[3];
  const float* sWroot = (const float*)d_in[4];
  const float* sb     = (const float*)d_in[5];
  const float* l1Wr   = (const float*)d_in[6];
  const float* l1Wroot= (const float*)d_in[7];
  const float* l1b    = (const float*)d_in[8];
  const float* l2Wr   = (const float*)d_in[9];
  const float* l2Wroot= (const float*)d_in[10];
  const float* l2b    = (const float*)d_in[11];
  const float* Wout   = (const float*)d_in[12];
  const float* bout   = (const float*)d_in[13];

  const int E = in_sizes[2];
  const int N = in_sizes[0] / (TT*FF);
  const int* src = ei;
  const int* dst = ei + E;

  float* out0   = (float*)d_out;              // [4,N,8]
  float* c2out  = out0 + (size_t)NF*N*OO;     // [N,64]
  float* embout = c2out + (size_t)N*HH;       // [12,N,64]

  float* w = (float*)d_ws;
  float* cbuf   = w;  w += (size_t)N*HH;
  float* invd   = w;  w += N;
  int*   cnt    = (int*)w;  w += N;
  int*   fill   = (int*)w;  w += N;
  int*   ptr    = (int*)w;  w += (N+2);       // keep int2 array 8B-aligned
  int2*  csr_sw = (int2*)w; w += (size_t)2*E;
  unsigned short* Wf1 = (unsigned short*)w; w += (size_t)16*8*64*8/2;
  unsigned short* Wf2 = (unsigned short*)w; w += (size_t)16*8*64*8/2;
  unsigned short* Sfg = (unsigned short*)w; w += (size_t)4*2*64*8/2;
  unsigned short* xb     = (unsigned short*)w; w += (size_t)TT*N*FF/2;
  unsigned short* aggb   = (unsigned short*)w; w += (size_t)TT*N*FF/2;
  unsigned short* xrb    = (unsigned short*)w; w += (size_t)TT*N*HH/2;
  unsigned short* xraggb = (unsigned short*)w; w += (size_t)TT*N*HH/2;
  unsigned short* hA     = (unsigned short*)w; w += (size_t)N*HH/2;
  unsigned short* hB     = (unsigned short*)w; w += (size_t)N*HH/2;
  unsigned short* h2s    = (unsigned short*)w; w += (size_t)NF*N*HH/2;

  hipMemsetAsync(cnt,  0, (size_t)N*4, stream);
  hipMemsetAsync(fill, 0, (size_t)N*4, stream);
  hipMemsetAsync(hA,   0, (size_t)N*HH*2, stream);  // h0 (bf16 zero = 0)
  hipMemsetAsync(cbuf, 0, (size_t)N*HH*4, stream);  // c0

  hist_kernel<<<(E+255)/256, 256, 0, stream>>>(dst, cnt, E);
  scan_kernel<<<1, 1024, 0, stream>>>(cnt, ptr, invd, N);
  fill_kernel<<<(E+255)/256, 256, 0, stream>>>(src, dst, ew, ptr, fill, csr_sw, E);

  pack_wfrag<<<(16*8*64*8+255)/256, 256, 0, stream>>>(l1Wr, l1Wroot, Wf1);
  pack_wfrag<<<(16*8*64*8+255)/256, 256, 0, stream>>>(l2Wr, l2Wroot, Wf2);
  pack_sfrag<<<(4*2*64*8+255)/256, 256, 0, stream>>>(sWr, sWroot, Sfg);
  bf16_conv<<<((size_t)TT*N*FF+255)/256, 256, 0, stream>>>(x, xb, TT*N*FF);

  sage_gather<<<(N+3)/4, 256, 0, stream>>>(xb, ptr, csr_sw, invd, aggb, N);
  {
    int Mrows = TT*N;
    sage_mfma<<<(Mrows+63)/64, 256, 0, stream>>>(aggb, xb, Sfg, sb, embout, xrb, Mrows);
  }
  xr_gather<<<(N+3)/4, 256, 0, stream>>>(xrb, ptr, csr_sw, invd, xraggb, N);

  const int sBlocks = (N+BR-1)/BR;      // 1250
  unsigned short* hp = hA; unsigned short* hn = hB;
  // LSTM1
  for (int t = 0; t < TT; ++t){
    lstm_mfma<<<sBlocks, 1024, 0, stream>>>(xrb + (size_t)t*N*HH, xraggb + (size_t)t*N*HH,
                                            hp, hn, cbuf, invd, ptr, csr_sw,
                                            Wf1, l1b, nullptr, N);
    unsigned short* tmp = hp; hp = hn; hn = tmp;
  }
  // LSTM2 (continues from h1[-1], c1); h2 stored for t>=8
  for (int t = 0; t < TT; ++t){
    unsigned short* store = (t >= TT-NF) ? (h2s + (size_t)(t-(TT-NF))*N*HH) : nullptr;
    lstm_mfma<<<sBlocks, 1024, 0, stream>>>(xrb + (size_t)t*N*HH, xraggb + (size_t)t*N*HH,
                                            hp, hn, cbuf, invd, ptr, csr_sw,
                                            Wf2, l2b, store, N);
    unsigned short* tmp = hp; hp = hn; hn = tmp;
  }

  out_gemm<<<((size_t)NF*N*OO+255)/256, 256, 0, stream>>>(xrb + (size_t)(TT-NF)*N*HH, h2s,
                                                          Wout, bout, out0, N);
  copyk<<<((size_t)N*HH+255)/256, 256, 0, stream>>>(cbuf, c2out, N*HH);
}

// Round 14
// 1004.094 us; speedup vs baseline: 4.8775x; 1.1101x over previous
//
#include <hip/hip_runtime.h>
#include <math.h>

#define TT 12
#define FF 32
#define HH 64
#define OO 8
#define GG 256   // 4*HH
#define NF 4     // NUM_FUTURE
#define BR 16    // nodes per lstm block

typedef __bf16 bf16x8 __attribute__((ext_vector_type(8)));
typedef float  f32x4  __attribute__((ext_vector_type(4)));

__device__ __forceinline__ float sigmoidf_(float x){ return 1.f/(1.f+expf(-x)); }
__device__ __forceinline__ unsigned short f2bf(float f){   // round-to-nearest-even
  unsigned int u = __float_as_uint(f);
  u += 0x7FFFu + ((u >> 16) & 1u);
  return (unsigned short)(u >> 16);
}
__device__ __forceinline__ float bf2f(unsigned short b){
  return __uint_as_float(((unsigned int)b) << 16);
}

// ================= CSR build =================
__global__ void hist_kernel(const int* __restrict__ dst, int* __restrict__ cnt, int E){
  int e = blockIdx.x*blockDim.x + threadIdx.x;
  if (e < E) atomicAdd(&cnt[dst[e]], 1);
}

__global__ __launch_bounds__(1024) void scan_kernel(const int* __restrict__ cnt,
                                                    int* __restrict__ ptr,
                                                    float* __restrict__ invd, int N){
  __shared__ int buf[1024];
  __shared__ int carry;
  if (threadIdx.x == 0) carry = 0;
  __syncthreads();
  for (int base = 0; base < N; base += 1024){
    int i = base + threadIdx.x;
    int v = (i < N) ? cnt[i] : 0;
    buf[threadIdx.x] = v;
    __syncthreads();
    for (int off = 1; off < 1024; off <<= 1){
      int t = (threadIdx.x >= off) ? buf[threadIdx.x - off] : 0;
      __syncthreads();
      buf[threadIdx.x] += t;
      __syncthreads();
    }
    int incl = buf[threadIdx.x];
    if (i < N){
      ptr[i] = carry + incl - v;
      invd[i] = 1.f / fmaxf((float)v, 1.f);
    }
    __syncthreads();
    if (threadIdx.x == 1023){
      carry += incl;
      if (base + 1024 >= N) ptr[N] = carry;
    }
    __syncthreads();
  }
}

__global__ void fill_kernel(const int* __restrict__ src, const int* __restrict__ dst,
                            const float* __restrict__ ew, const int* __restrict__ ptr,
                            int* __restrict__ fill, int2* __restrict__ csr_sw, int E){
  int e = blockIdx.x*blockDim.x + threadIdx.x;
  if (e >= E) return;
  int d = dst[e];
  int pos = ptr[d] + atomicAdd(&fill[d], 1);
  int2 m; m.x = src[e]; m.y = __float_as_int(ew[e]);
  csr_sw[pos] = m;
}

// ====== fp32 [t][n][f] -> bf16 node-major [(n*TT+t)*FF+f] ======
__global__ void xpose_conv(const float* __restrict__ in, unsigned short* __restrict__ out,
                           int N){
  int idx = blockIdx.x*blockDim.x + threadIdx.x;
  if (idx >= TT*N*FF) return;
  int f = idx & (FF-1);
  int rem = idx >> 5;          // n*TT + t
  int t = rem % TT, n = rem / TT;
  out[idx] = f2bf(in[(size_t)t*N*FF + (size_t)n*FF + f]);
}

// ====== MFMA B-fragment weight packing (bf16), LSTM K=256 ======
__global__ void pack_wfrag(const float* __restrict__ Wr, const float* __restrict__ Wroot,
                           unsigned short* __restrict__ Wfrag){
  int idx = blockIdx.x*256 + threadIdx.x;
  if (idx >= 16*8*64*8) return;
  int e  = idx & 7;
  int l  = (idx >> 3) & 63;
  int ks = (idx >> 9) & 7;
  int jt = idx >> 12;
  int k = ks*32 + (l>>4)*8 + e;
  int j = jt*16 + (l&15);
  float v = (k < 128) ? Wr[(size_t)k*GG + j] : Wroot[(size_t)(k-128)*GG + j];
  Wfrag[idx] = f2bf(v);
}

// ====== MFMA B-fragment packing, SAGE K=64 ======
__global__ void pack_sfrag(const float* __restrict__ Wr, const float* __restrict__ Wroot,
                           unsigned short* __restrict__ Sfrag){
  int idx = blockIdx.x*256 + threadIdx.x;
  if (idx >= 4*2*64*8) return;
  int e  = idx & 7;
  int l  = (idx >> 3) & 63;
  int ks = (idx >> 9) & 1;
  int jt = idx >> 10;
  int k = ks*32 + (l>>4)*8 + e;   // 0..63
  int j = jt*16 + (l&15);
  float v = (k < 32) ? Wr[(size_t)k*HH + j] : Wroot[(size_t)(k-32)*HH + j];
  Sfrag[idx] = f2bf(v);
}

// ========== SAGE aggregation, node-major: per edge a 768B contiguous burst ==========
__global__ __launch_bounds__(256) void sage_gather(
    const unsigned short* __restrict__ xb, const int* __restrict__ ptr,
    const int2* __restrict__ csr_sw,
    const float* __restrict__ invd, unsigned short* __restrict__ aggb, int N){
  int wave = threadIdx.x >> 6, lane = threadIdx.x & 63;
  int f = lane & 31, tp = lane >> 5;
  int n = blockIdx.x*4 + wave;
  if (n >= N) return;
  int beg = ptr[n], end = ptr[n+1];
  float id = invd[n];
  float acc[TT/2];
  #pragma unroll
  for (int th = 0; th < TT/2; ++th) acc[th] = 0.f;
  int e = beg;
  for (; e+2 <= end; e += 2){
    int2 m0 = csr_sw[e], m1 = csr_sw[e+1];
    const unsigned short* p0 = xb + (size_t)m0.x*TT*FF + tp*FF + f;
    const unsigned short* p1 = xb + (size_t)m1.x*TT*FF + tp*FF + f;
    float w0 = __int_as_float(m0.y), w1 = __int_as_float(m1.y);
    #pragma unroll
    for (int th = 0; th < TT/2; ++th)
      acc[th] += bf2f(p0[2*th*FF])*w0 + bf2f(p1[2*th*FF])*w1;
  }
  for (; e < end; ++e){
    int2 m = csr_sw[e];
    const unsigned short* p = xb + (size_t)m.x*TT*FF + tp*FF + f;
    float wv = __int_as_float(m.y);
    #pragma unroll
    for (int th = 0; th < TT/2; ++th)
      acc[th] += bf2f(p[2*th*FF])*wv;
  }
  #pragma unroll
  for (int th = 0; th < TT/2; ++th)
    aggb[(size_t)n*TT*FF + (2*th+tp)*FF + f] = f2bf(acc[th] * id);  // pre-normalized
}

// ====== SAGE linear via MFMA over linear rows ro = n*TT+t ======
// emb (fp32, [t][n][h] output layout) ; xrb (bf16, node-major)
__global__ __launch_bounds__(256) void sage_mfma(
    const unsigned short* __restrict__ aggb, const unsigned short* __restrict__ xb,
    const unsigned short* __restrict__ Sfrag, const float* __restrict__ bias,
    float* __restrict__ emb, unsigned short* __restrict__ xrb, int N, int Mrows){
  int tid = threadIdx.x, wave = tid >> 6, lane = tid & 63;
  int rbase = blockIdx.x*64 + wave*16;
  if (rbase >= Mrows) return;
  int l15 = lane & 15, l4 = lane >> 4;
  int row = rbase + l15;
  bf16x8 af0 = *(const bf16x8*)&aggb[(size_t)row*FF + l4*8];   // k 0..31
  bf16x8 af1 = *(const bf16x8*)&xb  [(size_t)row*FF + l4*8];   // k 32..63
  f32x4 acc[4];
  #pragma unroll
  for (int jt = 0; jt < 4; ++jt){
    float bv = bias[jt*16 + l15];
    acc[jt][0]=bv; acc[jt][1]=bv; acc[jt][2]=bv; acc[jt][3]=bv;
  }
  #pragma unroll
  for (int jt = 0; jt < 4; ++jt){
    bf16x8 b0 = *(const bf16x8*)&Sfrag[(size_t)(((jt*2+0)*64) + lane) * 8];
    bf16x8 b1 = *(const bf16x8*)&Sfrag[(size_t)(((jt*2+1)*64) + lane) * 8];
    acc[jt] = __builtin_amdgcn_mfma_f32_16x16x32_bf16(af0, b0, acc[jt], 0, 0, 0);
    acc[jt] = __builtin_amdgcn_mfma_f32_16x16x32_bf16(af1, b1, acc[jt], 0, 0, 0);
  }
  #pragma unroll
  for (int jt = 0; jt < 4; ++jt){
    int col = jt*16 + l15;
    #pragma unroll
    for (int i = 0; i < 4; ++i){
      int ro = rbase + l4*4 + i;        // ro = n*TT + t
      int t = ro % TT, n = ro / TT;
      float v = acc[jt][i];
      emb[(size_t)t*N*HH + (size_t)n*HH + col] = v;
      xrb[(size_t)ro*HH + col] = f2bf(fmaxf(v, 0.f));
    }
  }
}

// ========== xr aggregation, node-major: per edge a 1536B contiguous burst ==========
__global__ __launch_bounds__(256) void xr_gather(
    const unsigned short* __restrict__ xrb, const int* __restrict__ ptr,
    const int2* __restrict__ csr_sw,
    const float* __restrict__ invd, unsigned short* __restrict__ xr_aggb, int N){
  int wave = threadIdx.x >> 6, lane = threadIdx.x & 63;
  int n = blockIdx.x*4 + wave;
  if (n >= N) return;
  int beg = ptr[n], end = ptr[n+1];
  float id = invd[n];
  float acc[TT];
  #pragma unroll
  for (int t = 0; t < TT; ++t) acc[t] = 0.f;
  int e = beg;
  for (; e+2 <= end; e += 2){
    int2 m0 = csr_sw[e], m1 = csr_sw[e+1];
    const unsigned short* p0 = xrb + (size_t)m0.x*TT*HH + lane;
    const unsigned short* p1 = xrb + (size_t)m1.x*TT*HH + lane;
    float w0 = __int_as_float(m0.y), w1 = __int_as_float(m1.y);
    #pragma unroll
    for (int t = 0; t < TT; ++t)
      acc[t] += bf2f(p0[t*HH])*w0 + bf2f(p1[t*HH])*w1;
  }
  for (; e < end; ++e){
    int2 m = csr_sw[e];
    const unsigned short* p = xrb + (size_t)m.x*TT*HH + lane;
    float wv = __int_as_float(m.y);
    #pragma unroll
    for (int t = 0; t < TT; ++t)
      acc[t] += bf2f(p[t*HH])*wv;
  }
  #pragma unroll
  for (int t = 0; t < TT; ++t)
    xr_aggb[(size_t)n*TT*HH + t*HH + lane] = f2bf(acc[t] * id);  // pre-normalized
}

// ====== fused step, 16 waves: per-wave h-gather + MFMA col-tile + cell ======
// xrb/xraggb node-major: row of (n,t) at (n*TT+t)*HH; pass base+t*HH, stride TT*HH.
__global__ __launch_bounds__(1024) void lstm_mfma(
    const unsigned short* __restrict__ xrb_t, const unsigned short* __restrict__ xraggb_t,
    const unsigned short* __restrict__ h_prev, unsigned short* __restrict__ h_next,
    float* __restrict__ c, const float* __restrict__ invd,
    const int* __restrict__ ptr, const int2* __restrict__ csr_sw,
    const unsigned short* __restrict__ Wfrag, const float* __restrict__ bias,
    unsigned short* __restrict__ h2_store, int N){
  __shared__ __align__(16) unsigned short Albuf[BR][264];  // bf16 A-tile, padded
  __shared__ float gbuf[BR][260];                          // fp32 gates
  int tid = threadIdx.x, wave = tid >> 6, lane = tid & 63;
  int base = blockIdx.x * BR;
  int n = base + wave;                  // this wave's node

  // ---- Phase A: one row per wave, gather h_agg (unroll-8) + stage bf16 A-tile ----
  if (n < N){
    float id = invd[n];
    int beg = ptr[n], end = ptr[n+1];
    float a0=0.f,a1=0.f,a2=0.f,a3=0.f,a4=0.f,a5=0.f,a6=0.f,a7=0.f;
    int e = beg;
    for (; e+8 <= end; e += 8){
      int2 m0=csr_sw[e+0], m1=csr_sw[e+1], m2=csr_sw[e+2], m3=csr_sw[e+3];
      int2 m4=csr_sw[e+4], m5=csr_sw[e+5], m6=csr_sw[e+6], m7=csr_sw[e+7];
      a0 += bf2f(h_prev[(size_t)m0.x*HH+lane])*__int_as_float(m0.y);
      a1 += bf2f(h_prev[(size_t)m1.x*HH+lane])*__int_as_float(m1.y);
      a2 += bf2f(h_prev[(size_t)m2.x*HH+lane])*__int_as_float(m2.y);
      a3 += bf2f(h_prev[(size_t)m3.x*HH+lane])*__int_as_float(m3.y);
      a4 += bf2f(h_prev[(size_t)m4.x*HH+lane])*__int_as_float(m4.y);
      a5 += bf2f(h_prev[(size_t)m5.x*HH+lane])*__int_as_float(m5.y);
      a6 += bf2f(h_prev[(size_t)m6.x*HH+lane])*__int_as_float(m6.y);
      a7 += bf2f(h_prev[(size_t)m7.x*HH+lane])*__int_as_float(m7.y);
    }
    for (; e < end; ++e){
      int2 m = csr_sw[e];
      a0 += bf2f(h_prev[(size_t)m.x*HH+lane])*__int_as_float(m.y);
    }
    float hag = (((a0+a1)+(a2+a3))+((a4+a5)+(a6+a7))) * id;
    Albuf[wave][    lane] = xraggb_t[(size_t)n*TT*HH + lane];
    Albuf[wave][ 64+lane] = f2bf(hag);
    Albuf[wave][128+lane] = xrb_t [(size_t)n*TT*HH + lane];
    Albuf[wave][192+lane] = h_prev[(size_t)n*HH + lane];
  } else {
    Albuf[wave][lane] = Albuf[wave][64+lane] = Albuf[wave][128+lane] = Albuf[wave][192+lane] = 0;
  }
  __syncthreads();

  // ---- Phase B: wave owns col-tile jt = wave (cols 16w..16w+16), 8 MFMAs ----
  int l15 = lane & 15, l4 = lane >> 4;
  int jt = wave;
  f32x4 acc;
  {
    float bv = bias[jt*16 + l15];
    acc[0]=bv; acc[1]=bv; acc[2]=bv; acc[3]=bv;
  }
  #pragma unroll
  for (int ks = 0; ks < 8; ++ks){
    bf16x8 af = *(const bf16x8*)&Albuf[l15][ks*32 + l4*8];
    bf16x8 bf = *(const bf16x8*)&Wfrag[(size_t)(((jt*8 + ks)*64) + lane) * 8];
    acc = __builtin_amdgcn_mfma_f32_16x16x32_bf16(af, bf, acc, 0, 0, 0);
  }
  // D layout: col = lane&15, row = (lane>>4)*4 + i (m89-verified)
  {
    int col = jt*16 + l15;
    #pragma unroll
    for (int i = 0; i < 4; ++i)
      gbuf[l4*4 + i][col] = acc[i];
  }
  __syncthreads();

  // ---- Phase C: one row per wave ----
  if (n < N){
    int r = wave;
    float gi = gbuf[r][lane], gf = gbuf[r][64+lane], gg2 = gbuf[r][128+lane], go = gbuf[r][192+lane];
    float cn = sigmoidf_(gf)*c[(size_t)n*HH+lane] + sigmoidf_(gi)*tanhf(gg2);
    float hn = sigmoidf_(go)*tanhf(cn);
    c[(size_t)n*HH+lane] = cn;
    unsigned short hb = f2bf(hn);
    h_next[(size_t)n*HH+lane] = hb;
    if (h2_store) h2_store[(size_t)n*HH+lane] = hb;
  }
}

// ================= output head (bf16 inputs; xrb node-major) =================
__global__ void out_gemm(const unsigned short* __restrict__ xrb, const unsigned short* __restrict__ h2s,
                         const float* __restrict__ Wout, const float* __restrict__ bout,
                         float* __restrict__ out, int N){
  int idx = blockIdx.x*blockDim.x + threadIdx.x;
  if (idx >= NF*N*OO) return;
  int o = idx & (OO-1);
  int row = idx >> 3;                     // tt*N + n
  int tt = row / N, n = row % N;
  const unsigned short* xv = xrb + ((size_t)n*TT + (TT-NF) + tt)*HH;
  const unsigned short* hv = h2s + (size_t)row*HH;
  float acc = bout[o];
  #pragma unroll
  for (int k = 0; k < HH; ++k)
    acc += bf2f(xv[k])*Wout[k*OO+o] + bf2f(hv[k])*Wout[(HH+k)*OO+o];
  out[idx] = acc;
}

__global__ void copyk(const float* __restrict__ s, float* __restrict__ d, int n){
  int i = blockIdx.x*blockDim.x + threadIdx.x;
  if (i < n) d[i] = s[i];
}

extern "C" void kernel_launch(void* const* d_in, const int* in_sizes, int n_in,
                              void* d_out, int out_size, void* d_ws, size_t ws_size,
                              hipStream_t stream){
  const float* x      = (const float*)d_in[0];
  const int*   ei     = (const int*)  d_in[1];
  const float* ew     = (const float*)d_in[2];
  const float* sWr    = (const float*)d_in[3];
  const float* sWroot = (const float*)d_in[4];
  const float* sb     = (const float*)d_in[5];
  const float* l1Wr   = (const float*)d_in[6];
  const float* l1Wroot= (const float*)d_in[7];
  const float* l1b    = (const float*)d_in[8];
  const float* l2Wr   = (const float*)d_in[9];
  const float* l2Wroot= (const float*)d_in[10];
  const float* l2b    = (const float*)d_in[11];
  const float* Wout   = (const float*)d_in[12];
  const float* bout   = (const float*)d_in[13];

  const int E = in_sizes[2];
  const int N = in_sizes[0] / (TT*FF);
  const int* src = ei;
  const int* dst = ei + E;

  float* out0   = (float*)d_out;              // [4,N,8]
  float* c2out  = out0 + (size_t)NF*N*OO;     // [N,64]
  float* embout = c2out + (size_t)N*HH;       // [12,N,64]

  float* w = (float*)d_ws;
  float* cbuf   = w;  w += (size_t)N*HH;
  float* invd   = w;  w += N;
  int*   cnt    = (int*)w;  w += N;
  int*   fill   = (int*)w;  w += N;
  int*   ptr    = (int*)w;  w += (N+2);       // keep int2 array 8B-aligned
  int2*  csr_sw = (int2*)w; w += (size_t)2*E;
  unsigned short* Wf1 = (unsigned short*)w; w += (size_t)16*8*64*8/2;
  unsigned short* Wf2 = (unsigned short*)w; w += (size_t)16*8*64*8/2;
  unsigned short* Sfg = (unsigned short*)w; w += (size_t)4*2*64*8/2;
  unsigned short* xb     = (unsigned short*)w; w += (size_t)TT*N*FF/2;
  unsigned short* aggb   = (unsigned short*)w; w += (size_t)TT*N*FF/2;
  unsigned short* xrb    = (unsigned short*)w; w += (size_t)TT*N*HH/2;
  unsigned short* xraggb = (unsigned short*)w; w += (size_t)TT*N*HH/2;
  unsigned short* hA     = (unsigned short*)w; w += (size_t)N*HH/2;
  unsigned short* hB     = (unsigned short*)w; w += (size_t)N*HH/2;
  unsigned short* h2s    = (unsigned short*)w; w += (size_t)NF*N*HH/2;

  hipMemsetAsync(cnt,  0, (size_t)N*4, stream);
  hipMemsetAsync(fill, 0, (size_t)N*4, stream);
  hipMemsetAsync(hA,   0, (size_t)N*HH*2, stream);  // h0 (bf16 zero = 0)
  hipMemsetAsync(cbuf, 0, (size_t)N*HH*4, stream);  // c0

  hist_kernel<<<(E+255)/256, 256, 0, stream>>>(dst, cnt, E);
  scan_kernel<<<1, 1024, 0, stream>>>(cnt, ptr, invd, N);
  fill_kernel<<<(E+255)/256, 256, 0, stream>>>(src, dst, ew, ptr, fill, csr_sw, E);

  pack_wfrag<<<(16*8*64*8+255)/256, 256, 0, stream>>>(l1Wr, l1Wroot, Wf1);
  pack_wfrag<<<(16*8*64*8+255)/256, 256, 0, stream>>>(l2Wr, l2Wroot, Wf2);
  pack_sfrag<<<(4*2*64*8+255)/256, 256, 0, stream>>>(sWr, sWroot, Sfg);
  xpose_conv<<<((size_t)TT*N*FF+255)/256, 256, 0, stream>>>(x, xb, N);

  sage_gather<<<(N+3)/4, 256, 0, stream>>>(xb, ptr, csr_sw, invd, aggb, N);
  {
    int Mrows = TT*N;
    sage_mfma<<<(Mrows+63)/64, 256, 0, stream>>>(aggb, xb, Sfg, sb, embout, xrb, N, Mrows);
  }
  xr_gather<<<(N+3)/4, 256, 0, stream>>>(xrb, ptr, csr_sw, invd, xraggb, N);

  const int sBlocks = (N+BR-1)/BR;      // 1250
  unsigned short* hp = hA; unsigned short* hn = hB;
  // LSTM1
  for (int t = 0; t < TT; ++t){
    lstm_mfma<<<sBlocks, 1024, 0, stream>>>(xrb + (size_t)t*HH, xraggb + (size_t)t*HH,
                                            hp, hn, cbuf, invd, ptr, csr_sw,
                                            Wf1, l1b, nullptr, N);
    unsigned short* tmp = hp; hp = hn; hn = tmp;
  }
  // LSTM2 (continues from h1[-1], c1); h2 stored for t>=8
  for (int t = 0; t < TT; ++t){
    unsigned short* store = (t >= TT-NF) ? (h2s + (size_t)(t-(TT-NF))*N*HH) : nullptr;
    lstm_mfma<<<sBlocks, 1024, 0, stream>>>(xrb + (size_t)t*HH, xraggb + (size_t)t*HH,
                                            hp, hn, cbuf, invd, ptr, csr_sw,
                                            Wf2, l2b, store, N);
    unsigned short* tmp = hp; hp = hn; hn = tmp;
  }

  out_gemm<<<((size_t)NF*N*OO+255)/256, 256, 0, stream>>>(xrb, h2s,
                                                          Wout, bout, out0, N);
  copyk<<<((size_t)N*HH+255)/256, 256, 0, stream>>>(cbuf, c2out, N*HH);
}